// Round 4
// baseline (638.003 us; speedup 1.0000x reference)
//
#include <hip/hip_runtime.h>

// ---------------------------------------------------------------------------
// GNNQNetwork hetero-GAT, MI355X fp32. Round 8.
//
// R8 changes vs R7 (both edge kernels' inner math unchanged where passing):
//  1. edgeA regression fix: R7 gathered the 4B ls word from fat 64B/32B src
//     records (12.8MB sparse footprint per rv role, FETCH 210MB). Now a
//     dense LS6 array (4B per role-node, <=0.8MB per et) serves edgeA for
//     rv/t roles; r roles keep their compact 16B record. edgeB still reads
//     ls from the record line it needs anyway for x.
//  2. Kernel count 7 -> 5 (~27us/boundary of inter-dispatch overhead
//     measured: dispatch sum ~335us vs 527us total):
//       - precompute: now computes vsw/vdw directly as enc.(W@a) (no Cws,
//         no 128x128 C materialization) + zeroes P8.
//       - reduceP8 + finalize + out merged into tail_kernel: C-columns
//         recomputed on the fly (templated, register-unrolled), P8 summed
//         inline, xcat row kept in LDS, 512-wide output GEMV fused.
// ---------------------------------------------------------------------------

constexpr int kNT = 100000, kNRV = 200000, kNR = 300000, kE = 400000;
constexpr int kSLOT = 1088;        // per-et P tile: 16x64 acc + 64 cnt
constexpr int kPSZ  = 6 * kSLOT;   // 6528
constexpr int kNBE  = 342;         // blocks per edge type
constexpr int kNTH  = kNBE * 256;  // 87552 threads per edge type
constexpr int kEPT  = 5;           // edge slots per thread (5*87552 >= 400k)

// workspace offsets in 4-byte units (total 33.01 MB < proven 34.61 MB)
constexpr long long OFF_VS   = 0;        // 6*20
constexpr long long OFF_VD   = 120;      // 6*20
constexpr long long OFF_P8   = 256;      // 8 staged P copies: 8*6528 = 52224
constexpr long long OFF_LS6  = 52480;    // dense ls: rv roles @0/200k, t roles @400k/500k
constexpr long long OFF_SRV  = 652480;   // rv recs: 200k * 16 floats (64B)
constexpr long long OFF_ST   = 3852480;  // t recs: 100k * 8 floats (32B)
constexpr long long OFF_SR   = 4652480;  // r recs: 300k * 4 floats (16B)
constexpr long long OFF_LDD  = 5852480;  // dst recs {ld|b, denom}: 1.2M*8B
// end 8252480 floats = 33.01 MB

// per-et tables. src type: rv,t,r,rv,t,r ; dst type: t,rv,rv,r,r,t
__constant__ const int kDRB[6]  = {0, 100000, 300000, 500000, 800000, 1100000};
__constant__ const int kDLEN[6] = {100000, 200000, 200000, 300000, 300000, 100000};
__constant__ const int kLSB6[6] = {0, 400000, 0, 200000, 500000, 0}; // ets 2,5 unused

// ---------------------------------------------------------------------------
__device__ __forceinline__ int lowb(const int* a, int n, int v) {
  int lo = 0, hi = n;
  while (lo < hi) { int mid = (lo + hi) >> 1; if (a[mid] < v) lo = mid + 1; else hi = mid; }
  return lo;
}

static __device__ __forceinline__ unsigned p2h(float a, float b) {
  _Float16 ha = (_Float16)a, hb = (_Float16)b;
  unsigned short ua = __builtin_bit_cast(unsigned short, ha);
  unsigned short ub = __builtin_bit_cast(unsigned short, hb);
  return (unsigned)ua | ((unsigned)ub << 16);
}

// embed batch id (0..63) into low 6 mantissa bits of ld
static __device__ __forceinline__ float emb(float ld, int b) {
  return __uint_as_float((__float_as_uint(ld) & ~63u) | (unsigned)b);
}

// ---------------------------------------------------------------------------
// precompute: vsw/vdw = enc . (W @ a) per et (no C materialization) + P8 zero
__global__ __launch_bounds__(256) void precompute_kernel(
    const float* encW_t, const float* encb_t,
    const float* encW_rv, const float* encb_rv,
    const float* encW_r, const float* encb_r,
    const float* W0, const float* as0, const float* ad0,
    const float* W1, const float* as1, const float* ad1,
    const float* W2, const float* as2, const float* ad2,
    const float* W3, const float* as3, const float* ad3,
    const float* W4, const float* as4, const float* ad4,
    const float* W5, const float* as5, const float* ad5,
    float* vsw, float* vdw, float* P8)
{
  const float* encW[3] = {encW_t, encW_rv, encW_r};
  const float* encb[3] = {encb_t, encb_rv, encb_r};
  const int    Ks[3]   = {8, 13, 4};
  const float* Wv[6]  = {W0, W1, W2, W3, W4, W5};
  const float* asv[6] = {as0, as1, as2, as3, as4, as5};
  const float* adv[6] = {ad0, ad1, ad2, ad3, ad4, ad5};
  const int srcT[6] = {1, 0, 2, 1, 0, 2};
  const int dstT[6] = {0, 1, 1, 2, 2, 0};

  __shared__ float ws[128], wd[128];

  int et = blockIdx.x;
  int tid = threadIdx.x;
  int st = srcT[et], dt = dstT[et];
  const float* W = Wv[et];
  const float* a_s = asv[et];
  const float* a_d = adv[et];

  // zero P8 (grid-strided across the 6 blocks)
  for (int i = et * 256 + tid; i < 8 * kPSZ; i += 6 * 256) P8[i] = 0.f;

  if (tid < 128) {
    float accs = 0.f, accd = 0.f;
    const float* row = W + tid * 128;
    for (int j = 0; j < 128; ++j) {
      float w = row[j];
      accs += w * a_s[j];
      accd += w * a_d[j];
    }
    ws[tid] = accs;
    wd[tid] = accd;
  }
  __syncthreads();
  int K = Ks[st];
  if (tid <= K) {
    const float* row = (tid < K) ? (encW[st] + tid * 128) : encb[st];
    float acc = 0.f;
    for (int m = 0; m < 128; ++m) acc += row[m] * ws[m];
    vsw[et * 20 + (tid < K ? tid : 16)] = acc;
  }
  int KD = Ks[dt];
  if (tid >= 32 && tid <= 32 + KD) {
    int k = tid - 32;
    const float* row = (k < KD) ? (encW[dt] + k * 128) : encb[dt];
    float acc = 0.f;
    for (int m = 0; m < 128; ++m) acc += row[m] * wd[m];
    vdw[et * 20 + (k < KD ? k : 16)] = acc;
  }
}

// ---------------------------------------------------------------------------
__global__ __launch_bounds__(256) void prep_kernel(
    const float* __restrict__ x_t, const float* __restrict__ x_rv,
    const float* __restrict__ x_r,
    const int* __restrict__ bt, const int* __restrict__ brv,
    const int* __restrict__ br,
    const float* __restrict__ vsw, const float* __restrict__ vdw,
    uint4* __restrict__ SRVq, uint4* __restrict__ STq, uint4* __restrict__ SRq,
    float* __restrict__ LS6, float* __restrict__ LDDf)
{
  int n = blockIdx.x * 256 + threadIdx.x;
  if (n >= kNT + kNRV + kNR) return;
  if (n < kNT) {
    // tile: src roles et1,et4 (K=8); dst roles et0,et5
    const float* xr = x_t + n * 8;
    int b = bt[n];
    const float* vsA = vsw + 1 * 20, *vsB = vsw + 4 * 20;
    const float* vdA = vdw + 0 * 20, *vdB = vdw + 5 * 20;
    float x[8]; float a0 = 0, a1 = 0, a2 = 0, a3 = 0;
#pragma unroll
    for (int k = 0; k < 8; ++k) {
      x[k] = xr[k];
      a0 += x[k] * vsA[k]; a1 += x[k] * vsB[k];
      a2 += x[k] * vdA[k]; a3 += x[k] * vdB[k];
    }
    float ls1 = a0 + vsA[16], ls4 = a1 + vsB[16];
    float ld0 = a2 + vdA[16], ld5 = a3 + vdB[16];
    STq[(long long)n * 2] =
        make_uint4(p2h(x[0], x[1]), p2h(x[2], x[3]), p2h(x[4], x[5]), p2h(x[6], x[7]));
    STq[(long long)n * 2 + 1] =
        make_uint4(__float_as_uint(ls1), __float_as_uint(ls4), 0, 0);
    LS6[400000 + n] = ls1;
    LS6[500000 + n] = ls4;
    LDDf[(long long)n * 2] = emb(ld0, b);
    LDDf[(long long)n * 2 + 1] = 0.f;
    LDDf[(long long)(1100000 + n) * 2] = emb(ld5, b);
    LDDf[(long long)(1100000 + n) * 2 + 1] = 0.f;
  } else if (n < kNT + kNRV) {
    int m = n - kNT;
    // rv: src roles et0,et3 (K=13); dst roles et1,et2
    const float* xr = x_rv + m * 13;
    int b = brv[m];
    const float* vsA = vsw + 0 * 20, *vsB = vsw + 3 * 20;
    const float* vdA = vdw + 1 * 20, *vdB = vdw + 2 * 20;
    float x[13]; float a0 = 0, a1 = 0, a2 = 0, a3 = 0;
#pragma unroll
    for (int k = 0; k < 13; ++k) {
      x[k] = xr[k];
      a0 += x[k] * vsA[k]; a1 += x[k] * vsB[k];
      a2 += x[k] * vdA[k]; a3 += x[k] * vdB[k];
    }
    float ls0 = a0 + vsA[16], ls3 = a1 + vsB[16];
    float ld1 = a2 + vdA[16], ld2 = a3 + vdB[16];
    SRVq[(long long)m * 4] =
        make_uint4(p2h(x[0], x[1]), p2h(x[2], x[3]), p2h(x[4], x[5]), p2h(x[6], x[7]));
    SRVq[(long long)m * 4 + 1] =
        make_uint4(p2h(x[8], x[9]), p2h(x[10], x[11]), p2h(x[12], 0.f),
                   __float_as_uint(ls0));
    SRVq[(long long)m * 4 + 2] = make_uint4(__float_as_uint(ls3), 0, 0, 0);
    LS6[m] = ls0;
    LS6[200000 + m] = ls3;
    LDDf[(long long)(100000 + m) * 2] = emb(ld1, b);
    LDDf[(long long)(100000 + m) * 2 + 1] = 0.f;
    LDDf[(long long)(300000 + m) * 2] = emb(ld2, b);
    LDDf[(long long)(300000 + m) * 2 + 1] = 0.f;
  } else {
    int m = n - kNT - kNRV;
    // road: src roles et2,et5 (K=4); dst roles et3,et4
    const float* xr = x_r + m * 4;
    int b = br[m];
    const float* vsA = vsw + 2 * 20, *vsB = vsw + 5 * 20;
    const float* vdA = vdw + 3 * 20, *vdB = vdw + 4 * 20;
    float x[4]; float a0 = 0, a1 = 0, a2 = 0, a3 = 0;
#pragma unroll
    for (int k = 0; k < 4; ++k) {
      x[k] = xr[k];
      a0 += x[k] * vsA[k]; a1 += x[k] * vsB[k];
      a2 += x[k] * vdA[k]; a3 += x[k] * vdB[k];
    }
    float ls2 = a0 + vsA[16], ls5 = a1 + vsB[16];
    float ld3 = a2 + vdA[16], ld4 = a3 + vdB[16];
    SRq[m] = make_uint4(p2h(x[0], x[1]), p2h(x[2], x[3]),
                        __float_as_uint(ls2), __float_as_uint(ls5));
    LDDf[(long long)(500000 + m) * 2] = emb(ld3, b);
    LDDf[(long long)(500000 + m) * 2 + 1] = 0.f;
    LDDf[(long long)(800000 + m) * 2] = emb(ld4, b);
    LDDf[(long long)(800000 + m) * 2 + 1] = 0.f;
  }
}

// ---------------------------------------------------------------------------
__device__ __forceinline__ void pickSD(
    int et,
    const int* s0, const int* s1, const int* s2,
    const int* s3, const int* s4, const int* s5,
    const int* d0, const int* d1, const int* d2,
    const int* d3, const int* d4, const int* d5,
    const int*& sp, const int*& dp)
{
  switch (et) {
    case 0: sp = s0; dp = d0; break;
    case 1: sp = s1; dp = d1; break;
    case 2: sp = s2; dp = d2; break;
    case 3: sp = s3; dp = d3; break;
    case 4: sp = s4; dp = d4; break;
    default: sp = s5; dp = d5; break;
  }
}

// ---------------------------------------------------------------------------
// edgeA: w = exp(leaky(ls+ld)); denom += w. Dense LS6 for rv/t roles.
__global__ __launch_bounds__(256, 8) void edgeA_kernel(
    const int* s0, const int* s1, const int* s2,
    const int* s3, const int* s4, const int* s5,
    const int* d0, const int* d1, const int* d2,
    const int* d3, const int* d4, const int* d5,
    const unsigned* __restrict__ SRu, const float* __restrict__ LS6,
    float* __restrict__ LDDf)
{
  int et = blockIdx.x / kNBE;
  int bIdx = blockIdx.x - et * kNBE;
  const int* sp; const int* dp;
  pickSD(et, s0, s1, s2, s3, s4, s5, d0, d1, d2, d3, d4, d5, sp, dp);
  const int drb = kDRB[et];
  int base = bIdx * 256 + (int)threadIdx.x;

  int s[kEPT], d[kEPT]; bool ok[kEPT];
#pragma unroll
  for (int j = 0; j < kEPT; ++j) {
    int e = base + j * kNTH;
    ok[j] = e < kE;
    int ee = ok[j] ? e : 0;
    s[j] = sp[ee]; d[j] = dp[ee];
  }
  float ls[kEPT];
  if (et == 2 || et == 5) {
    const int lso = (et == 2) ? 2 : 3;
#pragma unroll
    for (int j = 0; j < kEPT; ++j)
      ls[j] = __uint_as_float(SRu[(long long)s[j] * 4 + lso]);
  } else {
    const float* L = LS6 + kLSB6[et];
#pragma unroll
    for (int j = 0; j < kEPT; ++j) ls[j] = L[s[j]];
  }
  float ld[kEPT];
#pragma unroll
  for (int j = 0; j < kEPT; ++j)
    ld[j] = LDDf[(long long)(drb + d[j]) * 2];
#pragma unroll
  for (int j = 0; j < kEPT; ++j) {
    float t = ls[j] + ld[j];
    t = t > 0.f ? t : 0.2f * t;
    float w = __expf(t);
    if (ok[j]) unsafeAtomicAdd(&LDDf[(long long)(drb + d[j]) * 2 + 1], w);
  }
}

// ---------------------------------------------------------------------------
// edgeB: recompute w from the record lines, alpha = w/denom, accumulate
// alpha*x into LDS [k][64 batches], then cnt, then dump to P8.
template <int TYPE, int RSEL>
__device__ __forceinline__ void ebflow(
    int bIdx,
    const int* __restrict__ sp, const int* __restrict__ dp,
    const uint4* __restrict__ srq, const float2* __restrict__ LDD2,
    int drb, int dlen, float* lp)
{
  constexpr int K = (TYPE == 0) ? 8 : ((TYPE == 1) ? 13 : 4);
  const int tid = threadIdx.x;
  const int lane = tid & 63;
  int base = bIdx * 256 + tid;

  int s[kEPT], d[kEPT]; bool ok[kEPT];
#pragma unroll
  for (int j = 0; j < kEPT; ++j) {
    int e = base + j * kNTH;
    ok[j] = e < kE;
    int ee = ok[j] ? e : 0;
    s[j] = sp[ee]; d[j] = dp[ee];
  }
  uint4 q0[kEPT], q1[kEPT];
  float lsx[kEPT];
#pragma unroll
  for (int j = 0; j < kEPT; ++j) {
    if (TYPE == 0) {
      q0[j] = srq[(long long)s[j] * 2];
      lsx[j] = __uint_as_float(
          ((const unsigned*)srq)[(long long)s[j] * 8 + (RSEL ? 5 : 4)]);
    } else if (TYPE == 1) {
      q0[j] = srq[(long long)s[j] * 4];
      q1[j] = srq[(long long)s[j] * 4 + 1];
      lsx[j] = RSEL
          ? __uint_as_float(((const unsigned*)srq)[(long long)s[j] * 16 + 8])
          : __uint_as_float(q1[j].w);
    } else {
      q0[j] = srq[s[j]];
      lsx[j] = __uint_as_float(RSEL ? q0[j].w : q0[j].z);
    }
  }
  float2 f2[kEPT];
#pragma unroll
  for (int j = 0; j < kEPT; ++j) f2[j] = LDD2[drb + d[j]];

#pragma unroll
  for (int j = 0; j < kEPT; ++j) {
    if (!ok[j]) continue;
    int b = (int)(__float_as_uint(f2[j].x) & 63u);
    float t = lsx[j] + f2[j].x;       // same bits as edgeA -> same w
    t = t > 0.f ? t : 0.2f * t;
    float w = __expf(t);
    float alpha = w / fmaxf(f2[j].y, 1e-16f);
    float xv[K];
    if (TYPE == 0) {
      const _Float16* h = (const _Float16*)&q0[j];
#pragma unroll
      for (int k = 0; k < 8; ++k) xv[k] = (float)h[k];
    } else if (TYPE == 1) {
      const _Float16* h = (const _Float16*)&q0[j];
#pragma unroll
      for (int k = 0; k < 8; ++k) xv[k] = (float)h[k];
      const _Float16* h2 = (const _Float16*)&q1[j];
#pragma unroll
      for (int k = 0; k < 5; ++k) xv[8 + k] = (float)h2[k];
    } else {
      const _Float16* h = (const _Float16*)&q0[j];
#pragma unroll
      for (int k = 0; k < 4; ++k) xv[k] = (float)h[k];
    }
#pragma unroll
    for (int k = 0; k < K; ++k) atomicAdd(lp + k * 64 + b, alpha * xv[k]);
  }

  // cnt: dst nodes with >=1 edge, per batch (wave-segmented scan)
  for (int base2 = bIdx * 256 + (tid & ~63); base2 < dlen; base2 += kNTH) {
    int j2 = base2 + lane;
    bool a2 = j2 < dlen;
    float2 r2 = a2 ? LDD2[drb + j2] : make_float2(0.f, 0.f);
    int b2 = a2 ? (int)(__float_as_uint(r2.x) & 63u) : (64 + lane);
    int v = (a2 && r2.y > 0.f) ? 1 : 0;
#pragma unroll
    for (int d2 = 1; d2 < 64; d2 <<= 1) {
      int ob = __shfl_up(b2, d2);
      int ov = __shfl_up(v, d2);
      if (lane >= d2 && ob == b2) v += ov;
    }
    int bn = __shfl_down(b2, 1);
    if (((lane == 63) || (bn != b2)) && v > 0) atomicAdd(lp + 1024 + b2, (float)v);
  }
}

__global__ __launch_bounds__(256, 4) void edgeB_kernel(
    const int* s0, const int* s1, const int* s2,
    const int* s3, const int* s4, const int* s5,
    const int* d0, const int* d1, const int* d2,
    const int* d3, const int* d4, const int* d5,
    const uint4* SRVq, const uint4* STq, const uint4* SRq,
    const float2* __restrict__ LDD2, float* __restrict__ P8)
{
  __shared__ float lp[kSLOT];
  for (int j = threadIdx.x; j < kSLOT; j += 256) lp[j] = 0.f;
  __syncthreads();
  int et = blockIdx.x / kNBE;
  int bIdx = blockIdx.x - et * kNBE;
  constexpr int KK[6] = {13, 8, 4, 13, 8, 4};
  switch (et) {
    case 0: ebflow<1, 0>(bIdx, s0, d0, SRVq, LDD2, 0,       100000, lp); break;
    case 1: ebflow<0, 0>(bIdx, s1, d1, STq,  LDD2, 100000,  200000, lp); break;
    case 2: ebflow<2, 0>(bIdx, s2, d2, SRq,  LDD2, 300000,  200000, lp); break;
    case 3: ebflow<1, 1>(bIdx, s3, d3, SRVq, LDD2, 500000,  300000, lp); break;
    case 4: ebflow<0, 1>(bIdx, s4, d4, STq,  LDD2, 800000,  300000, lp); break;
    default: ebflow<2, 1>(bIdx, s5, d5, SRq, LDD2, 1100000, 100000, lp); break;
  }
  __syncthreads();
  int K = KK[et];
  float* slab = P8 + (long long)(blockIdx.x & 7) * kPSZ + (long long)et * kSLOT;
  for (int i = threadIdx.x; i < kSLOT; i += 256) {
    if (i >= K * 64 && i < 1024) continue;
    float v = lp[i];
    if (v != 0.f) unsafeAtomicAdd(&slab[i], v);
  }
}

// ---------------------------------------------------------------------------
// tail: C-columns on the fly + P8 sum + pooled GAT rows + player MLP + out GEMV
template <int K>
__device__ __forceinline__ void colC(
    const float* __restrict__ W, const float* __restrict__ eW,
    const float* __restrict__ eb, int tid, float* __restrict__ outCol)
{
  float acc[K + 1];
#pragma unroll
  for (int k = 0; k <= K; ++k) acc[k] = 0.f;
  for (int m = 0; m < 128; ++m) {
    float w = W[m * 128 + tid];
#pragma unroll
    for (int k = 0; k < K; ++k) acc[k] += eW[k * 128 + m] * w;
    acc[K] += eb[m] * w;
  }
#pragma unroll
  for (int k = 0; k <= K; ++k) outCol[k * 128 + tid] = acc[k];
}

__global__ __launch_bounds__(128) void tail_kernel(
    const int* __restrict__ bt, const int* __restrict__ brv, const int* __restrict__ br,
    const float* __restrict__ xp,
    const float* __restrict__ fc1W, const float* __restrict__ fc1b,
    const float* __restrict__ fc2W, const float* __restrict__ fc2b,
    const float* __restrict__ outW, const float* __restrict__ outb,
    const float* W0, const float* W1, const float* W2,
    const float* W3, const float* W4, const float* W5,
    const float* encW_t, const float* encb_t,
    const float* encW_rv, const float* encb_rv,
    const float* encW_r, const float* encb_r,
    const float* __restrict__ b_rv2t, const float* __restrict__ b_r2t,
    const float* __restrict__ b_t2rv, const float* __restrict__ b_r2rv,
    const float* __restrict__ b_rv2r, const float* __restrict__ b_t2r,
    const float* __restrict__ P8, float* __restrict__ out)
{
  int b = blockIdx.x, tid = threadIdx.x;
  // C-col LDS: rows per et (K+1): 14,9,5,14,9,5 -> bases 0,14,23,28,42,51
  __shared__ float C[56 * 128];
  __shared__ float xrow[512];
  __shared__ float p1s[128];
  __shared__ float xps[64];
  __shared__ float psA[15], psB[15];
  __shared__ int cnts[3];

  if (tid < 64) xps[tid] = xp[b * 64 + tid];
  if (tid >= 64 && tid < 67) {
    int t = tid - 64;
    const int* ba = (t == 0) ? bt : (t == 1 ? brv : br);
    int N = (t == 0) ? kNT : (t == 1 ? kNRV : kNR);
    cnts[t] = lowb(ba, N, b + 1) - lowb(ba, N, b);
  }

  colC<13>(W0, encW_rv, encb_rv, tid, C + 0 * 128);
  colC<8>(W1, encW_t, encb_t, tid, C + 14 * 128);
  colC<4>(W2, encW_r, encb_r, tid, C + 23 * 128);
  colC<13>(W3, encW_rv, encb_rv, tid, C + 28 * 128);
  colC<8>(W4, encW_t, encb_t, tid, C + 42 * 128);
  colC<4>(W5, encW_r, encb_r, tid, C + 51 * 128);
  __syncthreads();

  // player branch
  float a = fc1b[tid];
  for (int k = 0; k < 64; ++k) a += xps[k] * fc1W[k * 128 + tid];
  p1s[tid] = fmaxf(a, 0.f);
  __syncthreads();
  float a2 = fc2b[tid];
  for (int k = 0; k < 128; ++k) a2 += p1s[k] * fc2W[k * 128 + tid];
  xrow[384 + tid] = fmaxf(a2, 0.f);

  const int etA[3] = {0, 1, 3}, etB[3] = {5, 2, 4};
  const int bA[3] = {0, 14, 28}, bB[3] = {51, 23, 42};
  const int KAv[3] = {13, 8, 13}, KBv[3] = {4, 4, 8};
  for (int t3 = 0; t3 < 3; ++t3) {
    __syncthreads();
    int eA = etA[t3], eB = etB[t3];
    if (tid < 15) {
      int idx = (tid < 14) ? (tid * 64 + b) : (1024 + b);
      float sum = 0.f;
#pragma unroll
      for (int c = 0; c < 8; ++c) sum += P8[c * kPSZ + eA * kSLOT + idx];
      psA[tid] = sum;
    } else if (tid < 30) {
      int t = tid - 15;
      int idx = (t < 14) ? (t * 64 + b) : (1024 + b);
      float sum = 0.f;
#pragma unroll
      for (int c = 0; c < 8; ++c) sum += P8[c * kPSZ + eB * kSLOT + idx];
      psB[t] = sum;
    }
    __syncthreads();
    int KA = KAv[t3], KB = KBv[t3];
    const float* CA = C + bA[t3] * 128;
    const float* CB = C + bB[t3] * 128;
    float v = psA[14] * CA[KA * 128 + tid] + psB[14] * CB[KB * 128 + tid];
    for (int k = 0; k < KA; ++k) v += psA[k] * CA[k * 128 + tid];
    for (int k = 0; k < KB; ++k) v += psB[k] * CB[k * 128 + tid];
    float cnt = (float)max(cnts[t3], 1);
    const float* bb1 = (t3 == 0) ? b_rv2t : (t3 == 1 ? b_t2rv : b_rv2r);
    const float* bb2 = (t3 == 0) ? b_r2t  : (t3 == 1 ? b_r2rv : b_t2r);
    xrow[t3 * 128 + tid] = v / cnt + bb1[tid] + bb2[tid];
  }
  __syncthreads();

  // output GEMV: out[b, c] for c = tid + 128q
#pragma unroll
  for (int q = 0; q < 4; ++q) {
    int c = q * 128 + tid;
    float acc = outb[c];
#pragma unroll 8
    for (int k = 0; k < 512; ++k) acc += xrow[k] * outW[k * 512 + c];
    out[b * 512 + c] = acc;
  }
}

// ---------------------------------------------------------------------------
extern "C" void kernel_launch(void* const* d_in, const int* in_sizes, int n_in,
                              void* d_out, int out_size, void* d_ws, size_t ws_size,
                              hipStream_t stream) {
  const float* x_tile   = (const float*)d_in[0];
  const float* x_rv     = (const float*)d_in[1];
  const float* x_road   = (const float*)d_in[2];
  const float* x_player = (const float*)d_in[3];
  const float* enc_t_W  = (const float*)d_in[4];
  const float* enc_t_b  = (const float*)d_in[5];
  const float* enc_rv_W = (const float*)d_in[6];
  const float* enc_rv_b = (const float*)d_in[7];
  const float* enc_r_W  = (const float*)d_in[8];
  const float* enc_r_b  = (const float*)d_in[9];
  const float* W[6]; const float* As[6]; const float* Ad[6]; const float* Bb[6];
  for (int et = 0; et < 6; ++et) {
    W[et]  = (const float*)d_in[10 + 4 * et];
    As[et] = (const float*)d_in[11 + 4 * et];
    Ad[et] = (const float*)d_in[12 + 4 * et];
    Bb[et] = (const float*)d_in[13 + 4 * et];
  }
  const float* fc1W = (const float*)d_in[34];
  const float* fc1b = (const float*)d_in[35];
  const float* fc2W = (const float*)d_in[36];
  const float* fc2b = (const float*)d_in[37];
  const float* outW = (const float*)d_in[38];
  const float* outb = (const float*)d_in[39];
  const int* esrc[6]; const int* edst[6];
  for (int et = 0; et < 6; ++et) {
    esrc[et] = (const int*)d_in[40 + 2 * et];
    edst[et] = (const int*)d_in[41 + 2 * et];
  }
  const int* batch_t  = (const int*)d_in[52];
  const int* batch_rv = (const int*)d_in[53];
  const int* batch_r  = (const int*)d_in[54];

  float* wsF = (float*)d_ws;
  float* vsw  = wsF + OFF_VS;
  float* vdw  = wsF + OFF_VD;
  float* P8   = wsF + OFF_P8;
  float* LS6  = wsF + OFF_LS6;
  uint4* SRVq = (uint4*)(wsF + OFF_SRV);
  uint4* STq  = (uint4*)(wsF + OFF_ST);
  uint4* SRq  = (uint4*)(wsF + OFF_SR);
  float* LDDf = wsF + OFF_LDD;
  float2* LDD2 = (float2*)(wsF + OFF_LDD);
  float* out  = (float*)d_out;

  precompute_kernel<<<6, 256, 0, stream>>>(
      enc_t_W, enc_t_b, enc_rv_W, enc_rv_b, enc_r_W, enc_r_b,
      W[0], As[0], Ad[0], W[1], As[1], Ad[1], W[2], As[2], Ad[2],
      W[3], As[3], Ad[3], W[4], As[4], Ad[4], W[5], As[5], Ad[5],
      vsw, vdw, P8);

  prep_kernel<<<(kNT + kNRV + kNR + 255) / 256, 256, 0, stream>>>(
      x_tile, x_rv, x_road, batch_t, batch_rv, batch_r, vsw, vdw,
      SRVq, STq, SRq, LS6, LDDf);

  edgeA_kernel<<<6 * kNBE, 256, 0, stream>>>(
      esrc[0], esrc[1], esrc[2], esrc[3], esrc[4], esrc[5],
      edst[0], edst[1], edst[2], edst[3], edst[4], edst[5],
      (const unsigned*)SRq, LS6, LDDf);

  edgeB_kernel<<<6 * kNBE, 256, 0, stream>>>(
      esrc[0], esrc[1], esrc[2], esrc[3], esrc[4], esrc[5],
      edst[0], edst[1], edst[2], edst[3], edst[4], edst[5],
      SRVq, STq, SRq, LDD2, P8);

  tail_kernel<<<64, 128, 0, stream>>>(
      batch_t, batch_rv, batch_r, x_player,
      fc1W, fc1b, fc2W, fc2b, outW, outb,
      W[0], W[1], W[2], W[3], W[4], W[5],
      enc_t_W, enc_t_b, enc_rv_W, enc_rv_b, enc_r_W, enc_r_b,
      Bb[0], Bb[5], Bb[1], Bb[2], Bb[3], Bb[4],
      P8, out);

  (void)in_sizes; (void)n_in; (void)out_size; (void)ws_size;
}

// Round 5
// 598.039 us; speedup vs baseline: 1.0668x; 1.0668x over previous
//
#include <hip/hip_runtime.h>

// ---------------------------------------------------------------------------
// GNNQNetwork hetero-GAT, MI355X fp32. Round 9.
//
// R9 = R8 with the tail regression fixed:
//   - R8's tail_kernel recomputed the 56x128 C matrix per block (64 blocks
//     x 917k MACs redundant, 1.5% occupancy, 186us). Restore R7's Cws
//     materialization in precompute_kernel (6 blocks, parallel, ~10us) and
//     make the tail READ Cws.
//   - tail keeps the useful fusions: P8 partial-sum + pooled GAT rows +
//     player MLP + 512-wide output GEMV in ONE kernel -> 5 kernels total.
//   - edgeA/edgeB/prep unchanged from R8 (edgeA uses dense LS6 for rv/t
//     roles, fixing R7's 210MB record-gather FETCH).
// ---------------------------------------------------------------------------

constexpr int kNT = 100000, kNRV = 200000, kNR = 300000, kE = 400000;
constexpr int kSLOT = 1088;        // per-et P tile: 16x64 acc + 64 cnt
constexpr int kPSZ  = 6 * kSLOT;   // 6528
constexpr int kNBE  = 342;         // blocks per edge type
constexpr int kNTH  = kNBE * 256;  // 87552 threads per edge type
constexpr int kEPT  = 5;           // edge slots per thread (5*87552 >= 400k)

// workspace offsets in 4-byte units (total 33.06 MB < proven 34.61 MB)
constexpr long long OFF_C    = 0;        // 6*2176 C rows + bias@2048
constexpr long long OFF_VS   = 13056;    // 6*20
constexpr long long OFF_VD   = 13176;    // 6*20
constexpr long long OFF_P8   = 13296;    // 8 staged P copies: 8*6528 = 52224
constexpr long long OFF_LS6  = 65520;    // dense ls: rv @0/200k, t @400k/500k
constexpr long long OFF_SRV  = 665520;   // rv recs: 200k * 16 floats (64B)
constexpr long long OFF_ST   = 3865520;  // t recs: 100k * 8 floats (32B)
constexpr long long OFF_SR   = 4665520;  // r recs: 300k * 4 floats (16B)
constexpr long long OFF_LDD  = 5865520;  // dst recs {ld|b, denom}: 1.2M*8B
// end 8265520 floats = 33.06 MB

// per-et tables. src type: rv,t,r,rv,t,r ; dst type: t,rv,rv,r,r,t
__constant__ const int kDRB[6]  = {0, 100000, 300000, 500000, 800000, 1100000};
__constant__ const int kDLEN[6] = {100000, 200000, 200000, 300000, 300000, 100000};
__constant__ const int kLSB6[6] = {0, 400000, 0, 200000, 500000, 0}; // ets 2,5 unused

// ---------------------------------------------------------------------------
__device__ __forceinline__ int lowb(const int* a, int n, int v) {
  int lo = 0, hi = n;
  while (lo < hi) { int mid = (lo + hi) >> 1; if (a[mid] < v) lo = mid + 1; else hi = mid; }
  return lo;
}

static __device__ __forceinline__ unsigned p2h(float a, float b) {
  _Float16 ha = (_Float16)a, hb = (_Float16)b;
  unsigned short ua = __builtin_bit_cast(unsigned short, ha);
  unsigned short ub = __builtin_bit_cast(unsigned short, hb);
  return (unsigned)ua | ((unsigned)ub << 16);
}

// embed batch id (0..63) into low 6 mantissa bits of ld
static __device__ __forceinline__ float emb(float ld, int b) {
  return __uint_as_float((__float_as_uint(ld) & ~63u) | (unsigned)b);
}

// ---------------------------------------------------------------------------
// precompute: C = enc @ W (rows 0..K-1, bias row @2048), vsw/vdw, P8 zero
__global__ __launch_bounds__(256) void precompute_kernel(
    const float* encW_t, const float* encb_t,
    const float* encW_rv, const float* encb_rv,
    const float* encW_r, const float* encb_r,
    const float* W0, const float* as0, const float* ad0,
    const float* W1, const float* as1, const float* ad1,
    const float* W2, const float* as2, const float* ad2,
    const float* W3, const float* as3, const float* ad3,
    const float* W4, const float* as4, const float* ad4,
    const float* W5, const float* as5, const float* ad5,
    float* Cws, float* vsw, float* vdw, float* P8)
{
  const float* encW[3] = {encW_t, encW_rv, encW_r};
  const float* encb[3] = {encb_t, encb_rv, encb_r};
  const int    Ks[3]   = {8, 13, 4};
  const float* Wv[6]  = {W0, W1, W2, W3, W4, W5};
  const float* asv[6] = {as0, as1, as2, as3, as4, as5};
  const float* adv[6] = {ad0, ad1, ad2, ad3, ad4, ad5};
  const int srcT[6] = {1, 0, 2, 1, 0, 2};
  const int dstT[6] = {0, 1, 1, 2, 2, 0};

  __shared__ float Cl[2176];
  __shared__ float wv[128];

  int et = blockIdx.x;
  int tid = threadIdx.x;
  int st = srcT[et], dt = dstT[et];
  const float* eW = encW[st];
  const float* eB = encb[st];
  int K = Ks[st];
  const float* W = Wv[et];
  const float* a_s = asv[et];
  const float* a_d = adv[et];
  float* Cslot = Cws + et * 2176;

  // zero P8 (grid-strided across the 6 blocks)
  for (int i = et * 256 + tid; i < 8 * kPSZ; i += 6 * 256) P8[i] = 0.f;

  for (int idx = tid; idx < (K + 1) * 128; idx += 256) {
    int r = idx >> 7, j = idx & 127;
    const float* row = (r < K) ? (eW + r * 128) : eB;
    float acc = 0.f;
    for (int m = 0; m < 128; ++m) acc += row[m] * W[m * 128 + j];
    int o = (r < K) ? (r * 128 + j) : (2048 + j);
    Cl[o] = acc;
    Cslot[o] = acc;
  }
  if (tid < 128) {
    float acc = 0.f;
    for (int j = 0; j < 128; ++j) acc += W[tid * 128 + j] * a_d[j];
    wv[tid] = acc;
  }
  __syncthreads();
  if (tid <= K) {
    const float* row = (tid < K) ? (Cl + tid * 128) : (Cl + 2048);
    float acc = 0.f;
    for (int j = 0; j < 128; ++j) acc += row[j] * a_s[j];
    vsw[et * 20 + (tid < K ? tid : 16)] = acc;
  }
  int KD = Ks[dt];
  if (tid >= 32 && tid <= 32 + KD) {
    int k = tid - 32;
    const float* row = (k < KD) ? (encW[dt] + k * 128) : encb[dt];
    float acc = 0.f;
    for (int m = 0; m < 128; ++m) acc += row[m] * wv[m];
    vdw[et * 20 + (k < KD ? k : 16)] = acc;
  }
}

// ---------------------------------------------------------------------------
__global__ __launch_bounds__(256) void prep_kernel(
    const float* __restrict__ x_t, const float* __restrict__ x_rv,
    const float* __restrict__ x_r,
    const int* __restrict__ bt, const int* __restrict__ brv,
    const int* __restrict__ br,
    const float* __restrict__ vsw, const float* __restrict__ vdw,
    uint4* __restrict__ SRVq, uint4* __restrict__ STq, uint4* __restrict__ SRq,
    float* __restrict__ LS6, float* __restrict__ LDDf)
{
  int n = blockIdx.x * 256 + threadIdx.x;
  if (n >= kNT + kNRV + kNR) return;
  if (n < kNT) {
    // tile: src roles et1,et4 (K=8); dst roles et0,et5
    const float* xr = x_t + n * 8;
    int b = bt[n];
    const float* vsA = vsw + 1 * 20, *vsB = vsw + 4 * 20;
    const float* vdA = vdw + 0 * 20, *vdB = vdw + 5 * 20;
    float x[8]; float a0 = 0, a1 = 0, a2 = 0, a3 = 0;
#pragma unroll
    for (int k = 0; k < 8; ++k) {
      x[k] = xr[k];
      a0 += x[k] * vsA[k]; a1 += x[k] * vsB[k];
      a2 += x[k] * vdA[k]; a3 += x[k] * vdB[k];
    }
    float ls1 = a0 + vsA[16], ls4 = a1 + vsB[16];
    float ld0 = a2 + vdA[16], ld5 = a3 + vdB[16];
    STq[(long long)n * 2] =
        make_uint4(p2h(x[0], x[1]), p2h(x[2], x[3]), p2h(x[4], x[5]), p2h(x[6], x[7]));
    STq[(long long)n * 2 + 1] =
        make_uint4(__float_as_uint(ls1), __float_as_uint(ls4), 0, 0);
    LS6[400000 + n] = ls1;
    LS6[500000 + n] = ls4;
    LDDf[(long long)n * 2] = emb(ld0, b);
    LDDf[(long long)n * 2 + 1] = 0.f;
    LDDf[(long long)(1100000 + n) * 2] = emb(ld5, b);
    LDDf[(long long)(1100000 + n) * 2 + 1] = 0.f;
  } else if (n < kNT + kNRV) {
    int m = n - kNT;
    // rv: src roles et0,et3 (K=13); dst roles et1,et2
    const float* xr = x_rv + m * 13;
    int b = brv[m];
    const float* vsA = vsw + 0 * 20, *vsB = vsw + 3 * 20;
    const float* vdA = vdw + 1 * 20, *vdB = vdw + 2 * 20;
    float x[13]; float a0 = 0, a1 = 0, a2 = 0, a3 = 0;
#pragma unroll
    for (int k = 0; k < 13; ++k) {
      x[k] = xr[k];
      a0 += x[k] * vsA[k]; a1 += x[k] * vsB[k];
      a2 += x[k] * vdA[k]; a3 += x[k] * vdB[k];
    }
    float ls0 = a0 + vsA[16], ls3 = a1 + vsB[16];
    float ld1 = a2 + vdA[16], ld2 = a3 + vdB[16];
    SRVq[(long long)m * 4] =
        make_uint4(p2h(x[0], x[1]), p2h(x[2], x[3]), p2h(x[4], x[5]), p2h(x[6], x[7]));
    SRVq[(long long)m * 4 + 1] =
        make_uint4(p2h(x[8], x[9]), p2h(x[10], x[11]), p2h(x[12], 0.f),
                   __float_as_uint(ls0));
    SRVq[(long long)m * 4 + 2] = make_uint4(__float_as_uint(ls3), 0, 0, 0);
    LS6[m] = ls0;
    LS6[200000 + m] = ls3;
    LDDf[(long long)(100000 + m) * 2] = emb(ld1, b);
    LDDf[(long long)(100000 + m) * 2 + 1] = 0.f;
    LDDf[(long long)(300000 + m) * 2] = emb(ld2, b);
    LDDf[(long long)(300000 + m) * 2 + 1] = 0.f;
  } else {
    int m = n - kNT - kNRV;
    // road: src roles et2,et5 (K=4); dst roles et3,et4
    const float* xr = x_r + m * 4;
    int b = br[m];
    const float* vsA = vsw + 2 * 20, *vsB = vsw + 5 * 20;
    const float* vdA = vdw + 3 * 20, *vdB = vdw + 4 * 20;
    float x[4]; float a0 = 0, a1 = 0, a2 = 0, a3 = 0;
#pragma unroll
    for (int k = 0; k < 4; ++k) {
      x[k] = xr[k];
      a0 += x[k] * vsA[k]; a1 += x[k] * vsB[k];
      a2 += x[k] * vdA[k]; a3 += x[k] * vdB[k];
    }
    float ls2 = a0 + vsA[16], ls5 = a1 + vsB[16];
    float ld3 = a2 + vdA[16], ld4 = a3 + vdB[16];
    SRq[m] = make_uint4(p2h(x[0], x[1]), p2h(x[2], x[3]),
                        __float_as_uint(ls2), __float_as_uint(ls5));
    LDDf[(long long)(500000 + m) * 2] = emb(ld3, b);
    LDDf[(long long)(500000 + m) * 2 + 1] = 0.f;
    LDDf[(long long)(800000 + m) * 2] = emb(ld4, b);
    LDDf[(long long)(800000 + m) * 2 + 1] = 0.f;
  }
}

// ---------------------------------------------------------------------------
__device__ __forceinline__ void pickSD(
    int et,
    const int* s0, const int* s1, const int* s2,
    const int* s3, const int* s4, const int* s5,
    const int* d0, const int* d1, const int* d2,
    const int* d3, const int* d4, const int* d5,
    const int*& sp, const int*& dp)
{
  switch (et) {
    case 0: sp = s0; dp = d0; break;
    case 1: sp = s1; dp = d1; break;
    case 2: sp = s2; dp = d2; break;
    case 3: sp = s3; dp = d3; break;
    case 4: sp = s4; dp = d4; break;
    default: sp = s5; dp = d5; break;
  }
}

// ---------------------------------------------------------------------------
// edgeA: w = exp(leaky(ls+ld)); denom += w. Dense LS6 for rv/t roles.
__global__ __launch_bounds__(256, 8) void edgeA_kernel(
    const int* s0, const int* s1, const int* s2,
    const int* s3, const int* s4, const int* s5,
    const int* d0, const int* d1, const int* d2,
    const int* d3, const int* d4, const int* d5,
    const unsigned* __restrict__ SRu, const float* __restrict__ LS6,
    float* __restrict__ LDDf)
{
  int et = blockIdx.x / kNBE;
  int bIdx = blockIdx.x - et * kNBE;
  const int* sp; const int* dp;
  pickSD(et, s0, s1, s2, s3, s4, s5, d0, d1, d2, d3, d4, d5, sp, dp);
  const int drb = kDRB[et];
  int base = bIdx * 256 + (int)threadIdx.x;

  int s[kEPT], d[kEPT]; bool ok[kEPT];
#pragma unroll
  for (int j = 0; j < kEPT; ++j) {
    int e = base + j * kNTH;
    ok[j] = e < kE;
    int ee = ok[j] ? e : 0;
    s[j] = sp[ee]; d[j] = dp[ee];
  }
  float ls[kEPT];
  if (et == 2 || et == 5) {
    const int lso = (et == 2) ? 2 : 3;
#pragma unroll
    for (int j = 0; j < kEPT; ++j)
      ls[j] = __uint_as_float(SRu[(long long)s[j] * 4 + lso]);
  } else {
    const float* L = LS6 + kLSB6[et];
#pragma unroll
    for (int j = 0; j < kEPT; ++j) ls[j] = L[s[j]];
  }
  float ld[kEPT];
#pragma unroll
  for (int j = 0; j < kEPT; ++j)
    ld[j] = LDDf[(long long)(drb + d[j]) * 2];
#pragma unroll
  for (int j = 0; j < kEPT; ++j) {
    float t = ls[j] + ld[j];
    t = t > 0.f ? t : 0.2f * t;
    float w = __expf(t);
    if (ok[j]) unsafeAtomicAdd(&LDDf[(long long)(drb + d[j]) * 2 + 1], w);
  }
}

// ---------------------------------------------------------------------------
// edgeB: recompute w from the record lines, alpha = w/denom, accumulate
// alpha*x into LDS [k][64 batches], then cnt, then dump to P8.
template <int TYPE, int RSEL>
__device__ __forceinline__ void ebflow(
    int bIdx,
    const int* __restrict__ sp, const int* __restrict__ dp,
    const uint4* __restrict__ srq, const float2* __restrict__ LDD2,
    int drb, int dlen, float* lp)
{
  constexpr int K = (TYPE == 0) ? 8 : ((TYPE == 1) ? 13 : 4);
  const int tid = threadIdx.x;
  const int lane = tid & 63;
  int base = bIdx * 256 + tid;

  int s[kEPT], d[kEPT]; bool ok[kEPT];
#pragma unroll
  for (int j = 0; j < kEPT; ++j) {
    int e = base + j * kNTH;
    ok[j] = e < kE;
    int ee = ok[j] ? e : 0;
    s[j] = sp[ee]; d[j] = dp[ee];
  }
  uint4 q0[kEPT], q1[kEPT];
  float lsx[kEPT];
#pragma unroll
  for (int j = 0; j < kEPT; ++j) {
    if (TYPE == 0) {
      q0[j] = srq[(long long)s[j] * 2];
      lsx[j] = __uint_as_float(
          ((const unsigned*)srq)[(long long)s[j] * 8 + (RSEL ? 5 : 4)]);
    } else if (TYPE == 1) {
      q0[j] = srq[(long long)s[j] * 4];
      q1[j] = srq[(long long)s[j] * 4 + 1];
      lsx[j] = RSEL
          ? __uint_as_float(((const unsigned*)srq)[(long long)s[j] * 16 + 8])
          : __uint_as_float(q1[j].w);
    } else {
      q0[j] = srq[s[j]];
      lsx[j] = __uint_as_float(RSEL ? q0[j].w : q0[j].z);
    }
  }
  float2 f2[kEPT];
#pragma unroll
  for (int j = 0; j < kEPT; ++j) f2[j] = LDD2[drb + d[j]];

#pragma unroll
  for (int j = 0; j < kEPT; ++j) {
    if (!ok[j]) continue;
    int b = (int)(__float_as_uint(f2[j].x) & 63u);
    float t = lsx[j] + f2[j].x;       // same bits as edgeA -> same w
    t = t > 0.f ? t : 0.2f * t;
    float w = __expf(t);
    float alpha = w / fmaxf(f2[j].y, 1e-16f);
    float xv[K];
    if (TYPE == 0) {
      const _Float16* h = (const _Float16*)&q0[j];
#pragma unroll
      for (int k = 0; k < 8; ++k) xv[k] = (float)h[k];
    } else if (TYPE == 1) {
      const _Float16* h = (const _Float16*)&q0[j];
#pragma unroll
      for (int k = 0; k < 8; ++k) xv[k] = (float)h[k];
      const _Float16* h2 = (const _Float16*)&q1[j];
#pragma unroll
      for (int k = 0; k < 5; ++k) xv[8 + k] = (float)h2[k];
    } else {
      const _Float16* h = (const _Float16*)&q0[j];
#pragma unroll
      for (int k = 0; k < 4; ++k) xv[k] = (float)h[k];
    }
#pragma unroll
    for (int k = 0; k < K; ++k) atomicAdd(lp + k * 64 + b, alpha * xv[k]);
  }

  // cnt: dst nodes with >=1 edge, per batch (wave-segmented scan)
  for (int base2 = bIdx * 256 + (tid & ~63); base2 < dlen; base2 += kNTH) {
    int j2 = base2 + lane;
    bool a2 = j2 < dlen;
    float2 r2 = a2 ? LDD2[drb + j2] : make_float2(0.f, 0.f);
    int b2 = a2 ? (int)(__float_as_uint(r2.x) & 63u) : (64 + lane);
    int v = (a2 && r2.y > 0.f) ? 1 : 0;
#pragma unroll
    for (int d2 = 1; d2 < 64; d2 <<= 1) {
      int ob = __shfl_up(b2, d2);
      int ov = __shfl_up(v, d2);
      if (lane >= d2 && ob == b2) v += ov;
    }
    int bn = __shfl_down(b2, 1);
    if (((lane == 63) || (bn != b2)) && v > 0) atomicAdd(lp + 1024 + b2, (float)v);
  }
}

__global__ __launch_bounds__(256, 4) void edgeB_kernel(
    const int* s0, const int* s1, const int* s2,
    const int* s3, const int* s4, const int* s5,
    const int* d0, const int* d1, const int* d2,
    const int* d3, const int* d4, const int* d5,
    const uint4* SRVq, const uint4* STq, const uint4* SRq,
    const float2* __restrict__ LDD2, float* __restrict__ P8)
{
  __shared__ float lp[kSLOT];
  for (int j = threadIdx.x; j < kSLOT; j += 256) lp[j] = 0.f;
  __syncthreads();
  int et = blockIdx.x / kNBE;
  int bIdx = blockIdx.x - et * kNBE;
  constexpr int KK[6] = {13, 8, 4, 13, 8, 4};
  switch (et) {
    case 0: ebflow<1, 0>(bIdx, s0, d0, SRVq, LDD2, 0,       100000, lp); break;
    case 1: ebflow<0, 0>(bIdx, s1, d1, STq,  LDD2, 100000,  200000, lp); break;
    case 2: ebflow<2, 0>(bIdx, s2, d2, SRq,  LDD2, 300000,  200000, lp); break;
    case 3: ebflow<1, 1>(bIdx, s3, d3, SRVq, LDD2, 500000,  300000, lp); break;
    case 4: ebflow<0, 1>(bIdx, s4, d4, STq,  LDD2, 800000,  300000, lp); break;
    default: ebflow<2, 1>(bIdx, s5, d5, SRq, LDD2, 1100000, 100000, lp); break;
  }
  __syncthreads();
  int K = KK[et];
  float* slab = P8 + (long long)(blockIdx.x & 7) * kPSZ + (long long)et * kSLOT;
  for (int i = threadIdx.x; i < kSLOT; i += 256) {
    if (i >= K * 64 && i < 1024) continue;
    float v = lp[i];
    if (v != 0.f) unsafeAtomicAdd(&slab[i], v);
  }
}

// ---------------------------------------------------------------------------
// tail: P8 sum + pooled GAT rows (reads Cws) + player MLP + output GEMV
__global__ __launch_bounds__(128) void tail_kernel(
    const int* __restrict__ bt, const int* __restrict__ brv, const int* __restrict__ br,
    const float* __restrict__ xp,
    const float* __restrict__ fc1W, const float* __restrict__ fc1b,
    const float* __restrict__ fc2W, const float* __restrict__ fc2b,
    const float* __restrict__ outW, const float* __restrict__ outb,
    const float* __restrict__ b_rv2t, const float* __restrict__ b_r2t,
    const float* __restrict__ b_t2rv, const float* __restrict__ b_r2rv,
    const float* __restrict__ b_rv2r, const float* __restrict__ b_t2r,
    const float* __restrict__ Cws, const float* __restrict__ P8,
    float* __restrict__ out)
{
  int b = blockIdx.x, tid = threadIdx.x;
  __shared__ float xrow[512];
  __shared__ float p1s[128];
  __shared__ float xps[64];
  __shared__ float psA[15], psB[15];
  __shared__ int cnts[3];

  if (tid < 64) xps[tid] = xp[b * 64 + tid];
  if (tid >= 64 && tid < 67) {
    int t = tid - 64;
    const int* ba = (t == 0) ? bt : (t == 1 ? brv : br);
    int N = (t == 0) ? kNT : (t == 1 ? kNRV : kNR);
    cnts[t] = lowb(ba, N, b + 1) - lowb(ba, N, b);
  }
  __syncthreads();

  // player branch
  float a = fc1b[tid];
  for (int k = 0; k < 64; ++k) a += xps[k] * fc1W[k * 128 + tid];
  p1s[tid] = fmaxf(a, 0.f);
  __syncthreads();
  float a2 = fc2b[tid];
  for (int k = 0; k < 128; ++k) a2 += p1s[k] * fc2W[k * 128 + tid];
  xrow[384 + tid] = fmaxf(a2, 0.f);

  const int etA[3] = {0, 1, 3}, etB[3] = {5, 2, 4};
  const int KAv[3] = {13, 8, 13}, KBv[3] = {4, 4, 8};
  for (int t3 = 0; t3 < 3; ++t3) {
    __syncthreads();
    int eA = etA[t3], eB = etB[t3];
    if (tid < 15) {
      int idx = (tid < 14) ? (tid * 64 + b) : (1024 + b);
      float sum = 0.f;
#pragma unroll
      for (int c = 0; c < 8; ++c) sum += P8[c * kPSZ + eA * kSLOT + idx];
      psA[tid] = sum;
    } else if (tid < 30) {
      int t = tid - 15;
      int idx = (t < 14) ? (t * 64 + b) : (1024 + b);
      float sum = 0.f;
#pragma unroll
      for (int c = 0; c < 8; ++c) sum += P8[c * kPSZ + eB * kSLOT + idx];
      psB[t] = sum;
    }
    __syncthreads();
    int KA = KAv[t3], KB = KBv[t3];
    const float* CA = Cws + eA * 2176;
    const float* CB = Cws + eB * 2176;
    float v = psA[14] * CA[2048 + tid] + psB[14] * CB[2048 + tid];
    for (int k = 0; k < KA; ++k) v += psA[k] * CA[k * 128 + tid];
    for (int k = 0; k < KB; ++k) v += psB[k] * CB[k * 128 + tid];
    float cnt = (float)max(cnts[t3], 1);
    const float* bb1 = (t3 == 0) ? b_rv2t : (t3 == 1 ? b_t2rv : b_rv2r);
    const float* bb2 = (t3 == 0) ? b_r2t  : (t3 == 1 ? b_r2rv : b_t2r);
    xrow[t3 * 128 + tid] = v / cnt + bb1[tid] + bb2[tid];
  }
  __syncthreads();

  // output GEMV: out[b, c] for c = tid + 128q
#pragma unroll
  for (int q = 0; q < 4; ++q) {
    int c = q * 128 + tid;
    float acc = outb[c];
#pragma unroll 8
    for (int k = 0; k < 512; ++k) acc += xrow[k] * outW[k * 512 + c];
    out[b * 512 + c] = acc;
  }
}

// ---------------------------------------------------------------------------
extern "C" void kernel_launch(void* const* d_in, const int* in_sizes, int n_in,
                              void* d_out, int out_size, void* d_ws, size_t ws_size,
                              hipStream_t stream) {
  const float* x_tile   = (const float*)d_in[0];
  const float* x_rv     = (const float*)d_in[1];
  const float* x_road   = (const float*)d_in[2];
  const float* x_player = (const float*)d_in[3];
  const float* enc_t_W  = (const float*)d_in[4];
  const float* enc_t_b  = (const float*)d_in[5];
  const float* enc_rv_W = (const float*)d_in[6];
  const float* enc_rv_b = (const float*)d_in[7];
  const float* enc_r_W  = (const float*)d_in[8];
  const float* enc_r_b  = (const float*)d_in[9];
  const float* W[6]; const float* As[6]; const float* Ad[6]; const float* Bb[6];
  for (int et = 0; et < 6; ++et) {
    W[et]  = (const float*)d_in[10 + 4 * et];
    As[et] = (const float*)d_in[11 + 4 * et];
    Ad[et] = (const float*)d_in[12 + 4 * et];
    Bb[et] = (const float*)d_in[13 + 4 * et];
  }
  const float* fc1W = (const float*)d_in[34];
  const float* fc1b = (const float*)d_in[35];
  const float* fc2W = (const float*)d_in[36];
  const float* fc2b = (const float*)d_in[37];
  const float* outW = (const float*)d_in[38];
  const float* outb = (const float*)d_in[39];
  const int* esrc[6]; const int* edst[6];
  for (int et = 0; et < 6; ++et) {
    esrc[et] = (const int*)d_in[40 + 2 * et];
    edst[et] = (const int*)d_in[41 + 2 * et];
  }
  const int* batch_t  = (const int*)d_in[52];
  const int* batch_rv = (const int*)d_in[53];
  const int* batch_r  = (const int*)d_in[54];

  float* wsF = (float*)d_ws;
  float* Cws  = wsF + OFF_C;
  float* vsw  = wsF + OFF_VS;
  float* vdw  = wsF + OFF_VD;
  float* P8   = wsF + OFF_P8;
  float* LS6  = wsF + OFF_LS6;
  uint4* SRVq = (uint4*)(wsF + OFF_SRV);
  uint4* STq  = (uint4*)(wsF + OFF_ST);
  uint4* SRq  = (uint4*)(wsF + OFF_SR);
  float* LDDf = wsF + OFF_LDD;
  float2* LDD2 = (float2*)(wsF + OFF_LDD);
  float* out  = (float*)d_out;

  precompute_kernel<<<6, 256, 0, stream>>>(
      enc_t_W, enc_t_b, enc_rv_W, enc_rv_b, enc_r_W, enc_r_b,
      W[0], As[0], Ad[0], W[1], As[1], Ad[1], W[2], As[2], Ad[2],
      W[3], As[3], Ad[3], W[4], As[4], Ad[4], W[5], As[5], Ad[5],
      Cws, vsw, vdw, P8);

  prep_kernel<<<(kNT + kNRV + kNR + 255) / 256, 256, 0, stream>>>(
      x_tile, x_rv, x_road, batch_t, batch_rv, batch_r, vsw, vdw,
      SRVq, STq, SRq, LS6, LDDf);

  edgeA_kernel<<<6 * kNBE, 256, 0, stream>>>(
      esrc[0], esrc[1], esrc[2], esrc[3], esrc[4], esrc[5],
      edst[0], edst[1], edst[2], edst[3], edst[4], edst[5],
      (const unsigned*)SRq, LS6, LDDf);

  edgeB_kernel<<<6 * kNBE, 256, 0, stream>>>(
      esrc[0], esrc[1], esrc[2], esrc[3], esrc[4], esrc[5],
      edst[0], edst[1], edst[2], edst[3], edst[4], edst[5],
      SRVq, STq, SRq, LDD2, P8);

  tail_kernel<<<64, 128, 0, stream>>>(
      batch_t, batch_rv, batch_r, x_player,
      fc1W, fc1b, fc2W, fc2b, outW, outb,
      Bb[0], Bb[5], Bb[1], Bb[2], Bb[3], Bb[4],
      Cws, P8, out);

  (void)in_sizes; (void)n_in; (void)out_size; (void)ws_size;
}

// Round 6
// 579.132 us; speedup vs baseline: 1.1017x; 1.0326x over previous
//
#include <hip/hip_runtime.h>

// ---------------------------------------------------------------------------
// GNNQNetwork hetero-GAT, MI355X fp32. Round 10.
//
// R10: R0's region-SEPARATED edge-phase memory layout (proven fastest:
// passA+passB ~245us) + all structural wins since:
//   - read-only dense gather arrays: LS6 (src logits, 4B), LD6 (dst logits,
//     4B). Atomic-only region: DEN float2 {denom, batch} (batch in .y,
//     written by prep, never touched by the .x atomics -> edgeB gets
//     denom+batch in ONE 8B load, no batch gather, no boundary search).
//     R9's load+RMW-same-line layout measurably regressed edgeA (148 vs
//     <124): read/atomic interference on hot lines. Regions now separate.
//   - W16 streamed w hand-off A->B (edge-order, coalesced both sides) ->
//     edgeB needs no ls -> src records are single-copy, ls-free x-only:
//     rv 32B, t 16B, r 8B (edgeB gather set 10.4MB, was ~25MB in R7).
//   - 5 kernels; P4 staged P copies; wave-segmented cnt scan.
// Workspace 34.56MB <= 34.61MB proven.
// ---------------------------------------------------------------------------

constexpr int kNT = 100000, kNRV = 200000, kNR = 300000, kE = 400000;
constexpr int kSLOT = 1088;        // per-et P tile: 16x64 acc + 64 cnt
constexpr int kPSZ  = 6 * kSLOT;   // 6528
constexpr int kNBE  = 342;         // blocks per edge type
constexpr int kNTH  = kNBE * 256;  // 87552 threads per edge type
constexpr int kEPT  = 5;           // edge slots per thread (5*87552 >= 400k)

// workspace offsets in 4-byte units (total 34.56 MB <= 34.61 proven)
constexpr long long OFF_C    = 0;        // 6*2176 C rows + bias@2048
constexpr long long OFF_VS   = 13056;    // 6*20
constexpr long long OFF_VD   = 13176;    // 6*20
constexpr long long OFF_P4   = 13296;    // 4 staged P copies: 4*6528 = 26112
constexpr long long OFF_LS6  = 39408;    // dense src logits, 1.2M
constexpr long long OFF_LD6  = 1239408;  // dense dst logits, 1.2M
constexpr long long OFF_W16  = 2439408;  // 2.4M halves = 1.2M floats
constexpr long long OFF_DEN  = 3639408;  // {den,batch} float2 x 1.2M = 2.4M
constexpr long long OFF_SRV  = 6039408;  // rv recs: 200k*8 floats (32B)
constexpr long long OFF_ST   = 7639408;  // t recs: 100k*4 floats (16B)
constexpr long long OFF_SR   = 8039408;  // r recs: 300k*2 floats (8B)
// end 8639408 floats = 34.558 MB

// per-et tables. src type: rv,t,r,rv,t,r ; dst type: t,rv,rv,r,r,t
__constant__ const int kDRB[6]  = {0, 100000, 300000, 500000, 800000, 1100000};
__constant__ const int kDLEN[6] = {100000, 200000, 200000, 300000, 300000, 100000};
__constant__ const int kLSB6[6] = {0, 400000, 600000, 200000, 500000, 900000};

// ---------------------------------------------------------------------------
__device__ __forceinline__ int lowb(const int* a, int n, int v) {
  int lo = 0, hi = n;
  while (lo < hi) { int mid = (lo + hi) >> 1; if (a[mid] < v) lo = mid + 1; else hi = mid; }
  return lo;
}

static __device__ __forceinline__ unsigned p2h(float a, float b) {
  _Float16 ha = (_Float16)a, hb = (_Float16)b;
  unsigned short ua = __builtin_bit_cast(unsigned short, ha);
  unsigned short ub = __builtin_bit_cast(unsigned short, hb);
  return (unsigned)ua | ((unsigned)ub << 16);
}

// ---------------------------------------------------------------------------
// precompute: C = enc @ W (rows 0..K-1, bias row @2048), vsw/vdw, P4 zero
__global__ __launch_bounds__(256) void precompute_kernel(
    const float* encW_t, const float* encb_t,
    const float* encW_rv, const float* encb_rv,
    const float* encW_r, const float* encb_r,
    const float* W0, const float* as0, const float* ad0,
    const float* W1, const float* as1, const float* ad1,
    const float* W2, const float* as2, const float* ad2,
    const float* W3, const float* as3, const float* ad3,
    const float* W4, const float* as4, const float* ad4,
    const float* W5, const float* as5, const float* ad5,
    float* Cws, float* vsw, float* vdw, float* P4)
{
  const float* encW[3] = {encW_t, encW_rv, encW_r};
  const float* encb[3] = {encb_t, encb_rv, encb_r};
  const int    Ks[3]   = {8, 13, 4};
  const float* Wv[6]  = {W0, W1, W2, W3, W4, W5};
  const float* asv[6] = {as0, as1, as2, as3, as4, as5};
  const float* adv[6] = {ad0, ad1, ad2, ad3, ad4, ad5};
  const int srcT[6] = {1, 0, 2, 1, 0, 2};
  const int dstT[6] = {0, 1, 1, 2, 2, 0};

  __shared__ float Cl[2176];
  __shared__ float wv[128];

  int et = blockIdx.x;
  int tid = threadIdx.x;
  int st = srcT[et], dt = dstT[et];
  const float* eW = encW[st];
  const float* eB = encb[st];
  int K = Ks[st];
  const float* W = Wv[et];
  const float* a_s = asv[et];
  const float* a_d = adv[et];
  float* Cslot = Cws + et * 2176;

  // zero P4 (grid-strided across the 6 blocks)
  for (int i = et * 256 + tid; i < 4 * kPSZ; i += 6 * 256) P4[i] = 0.f;

  for (int idx = tid; idx < (K + 1) * 128; idx += 256) {
    int r = idx >> 7, j = idx & 127;
    const float* row = (r < K) ? (eW + r * 128) : eB;
    float acc = 0.f;
    for (int m = 0; m < 128; ++m) acc += row[m] * W[m * 128 + j];
    int o = (r < K) ? (r * 128 + j) : (2048 + j);
    Cl[o] = acc;
    Cslot[o] = acc;
  }
  if (tid < 128) {
    float acc = 0.f;
    for (int j = 0; j < 128; ++j) acc += W[tid * 128 + j] * a_d[j];
    wv[tid] = acc;
  }
  __syncthreads();
  if (tid <= K) {
    const float* row = (tid < K) ? (Cl + tid * 128) : (Cl + 2048);
    float acc = 0.f;
    for (int j = 0; j < 128; ++j) acc += row[j] * a_s[j];
    vsw[et * 20 + (tid < K ? tid : 16)] = acc;
  }
  int KD = Ks[dt];
  if (tid >= 32 && tid <= 32 + KD) {
    int k = tid - 32;
    const float* row = (k < KD) ? (encW[dt] + k * 128) : encb[dt];
    float acc = 0.f;
    for (int m = 0; m < 128; ++m) acc += row[m] * wv[m];
    vdw[et * 20 + (k < KD ? k : 16)] = acc;
  }
}

// ---------------------------------------------------------------------------
// prep: per node, write x-only src recs, dense LS6/LD6 logits, DEN {0, b}.
__global__ __launch_bounds__(256) void prep_kernel(
    const float* __restrict__ x_t, const float* __restrict__ x_rv,
    const float* __restrict__ x_r,
    const int* __restrict__ bt, const int* __restrict__ brv,
    const int* __restrict__ br,
    const float* __restrict__ vsw, const float* __restrict__ vdw,
    uint4* __restrict__ SRVq, uint4* __restrict__ STq, uint2* __restrict__ SRq,
    float* __restrict__ LS6, float* __restrict__ LD6,
    float2* __restrict__ DEN)
{
  int n = blockIdx.x * 256 + threadIdx.x;
  if (n >= kNT + kNRV + kNR) return;
  if (n < kNT) {
    // tile: src roles et1,et4 (K=8); dst roles et0,et5
    const float* xr = x_t + n * 8;
    float bf = (float)bt[n];
    const float* vsA = vsw + 1 * 20, *vsB = vsw + 4 * 20;
    const float* vdA = vdw + 0 * 20, *vdB = vdw + 5 * 20;
    float x[8]; float a0 = 0, a1 = 0, a2 = 0, a3 = 0;
#pragma unroll
    for (int k = 0; k < 8; ++k) {
      x[k] = xr[k];
      a0 += x[k] * vsA[k]; a1 += x[k] * vsB[k];
      a2 += x[k] * vdA[k]; a3 += x[k] * vdB[k];
    }
    STq[n] = make_uint4(p2h(x[0], x[1]), p2h(x[2], x[3]),
                        p2h(x[4], x[5]), p2h(x[6], x[7]));
    LS6[400000 + n] = a0 + vsA[16];
    LS6[500000 + n] = a1 + vsB[16];
    LD6[n] = a2 + vdA[16];
    LD6[1100000 + n] = a3 + vdB[16];
    DEN[n] = make_float2(0.f, bf);
    DEN[1100000 + n] = make_float2(0.f, bf);
  } else if (n < kNT + kNRV) {
    int m = n - kNT;
    // rv: src roles et0,et3 (K=13); dst roles et1,et2
    const float* xr = x_rv + m * 13;
    float bf = (float)brv[m];
    const float* vsA = vsw + 0 * 20, *vsB = vsw + 3 * 20;
    const float* vdA = vdw + 1 * 20, *vdB = vdw + 2 * 20;
    float x[13]; float a0 = 0, a1 = 0, a2 = 0, a3 = 0;
#pragma unroll
    for (int k = 0; k < 13; ++k) {
      x[k] = xr[k];
      a0 += x[k] * vsA[k]; a1 += x[k] * vsB[k];
      a2 += x[k] * vdA[k]; a3 += x[k] * vdB[k];
    }
    SRVq[(long long)m * 2] =
        make_uint4(p2h(x[0], x[1]), p2h(x[2], x[3]), p2h(x[4], x[5]), p2h(x[6], x[7]));
    SRVq[(long long)m * 2 + 1] =
        make_uint4(p2h(x[8], x[9]), p2h(x[10], x[11]), p2h(x[12], 0.f), 0);
    LS6[m] = a0 + vsA[16];
    LS6[200000 + m] = a1 + vsB[16];
    LD6[100000 + m] = a2 + vdA[16];
    LD6[300000 + m] = a3 + vdB[16];
    DEN[100000 + m] = make_float2(0.f, bf);
    DEN[300000 + m] = make_float2(0.f, bf);
  } else {
    int m = n - kNT - kNRV;
    // road: src roles et2,et5 (K=4); dst roles et3,et4
    const float* xr = x_r + m * 4;
    float bf = (float)br[m];
    const float* vsA = vsw + 2 * 20, *vsB = vsw + 5 * 20;
    const float* vdA = vdw + 3 * 20, *vdB = vdw + 4 * 20;
    float x[4]; float a0 = 0, a1 = 0, a2 = 0, a3 = 0;
#pragma unroll
    for (int k = 0; k < 4; ++k) {
      x[k] = xr[k];
      a0 += x[k] * vsA[k]; a1 += x[k] * vsB[k];
      a2 += x[k] * vdA[k]; a3 += x[k] * vdB[k];
    }
    SRq[m] = make_uint2(p2h(x[0], x[1]), p2h(x[2], x[3]));
    LS6[600000 + m] = a0 + vsA[16];
    LS6[900000 + m] = a1 + vsB[16];
    LD6[500000 + m] = a2 + vdA[16];
    LD6[800000 + m] = a3 + vdB[16];
    DEN[500000 + m] = make_float2(0.f, bf);
    DEN[800000 + m] = make_float2(0.f, bf);
  }
}

// ---------------------------------------------------------------------------
__device__ __forceinline__ void pickSD(
    int et,
    const int* s0, const int* s1, const int* s2,
    const int* s3, const int* s4, const int* s5,
    const int* d0, const int* d1, const int* d2,
    const int* d3, const int* d4, const int* d5,
    const int*& sp, const int*& dp)
{
  switch (et) {
    case 0: sp = s0; dp = d0; break;
    case 1: sp = s1; dp = d1; break;
    case 2: sp = s2; dp = d2; break;
    case 3: sp = s3; dp = d3; break;
    case 4: sp = s4; dp = d4; break;
    default: sp = s5; dp = d5; break;
  }
}

// ---------------------------------------------------------------------------
// edgeA: w = exp(leaky(ls+ld)); W16[i] = w (streamed); DEN.x += w (atomic).
// Read-only gathers (LS6, LD6) fully separated from the atomic region (DEN).
__global__ __launch_bounds__(256, 8) void edgeA_kernel(
    const int* s0, const int* s1, const int* s2,
    const int* s3, const int* s4, const int* s5,
    const int* d0, const int* d1, const int* d2,
    const int* d3, const int* d4, const int* d5,
    const float* __restrict__ LS6, const float* __restrict__ LD6,
    _Float16* __restrict__ W16, float* __restrict__ DENf)
{
  int et = blockIdx.x / kNBE;
  int bIdx = blockIdx.x - et * kNBE;
  const int* sp; const int* dp;
  pickSD(et, s0, s1, s2, s3, s4, s5, d0, d1, d2, d3, d4, d5, sp, dp);
  const float* Lsrc = LS6 + kLSB6[et];
  const float* Ldst = LD6 + kDRB[et];
  const int drb = kDRB[et];
  _Float16* Wet = W16 + (long long)et * kE;
  int base = bIdx * 256 + (int)threadIdx.x;

  int s[kEPT], d[kEPT]; bool ok[kEPT];
#pragma unroll
  for (int j = 0; j < kEPT; ++j) {
    int e = base + j * kNTH;
    ok[j] = e < kE;
    int ee = ok[j] ? e : 0;
    s[j] = sp[ee]; d[j] = dp[ee];
  }
  float ls[kEPT];
#pragma unroll
  for (int j = 0; j < kEPT; ++j) ls[j] = Lsrc[s[j]];
  float ld[kEPT];
#pragma unroll
  for (int j = 0; j < kEPT; ++j) ld[j] = Ldst[d[j]];
#pragma unroll
  for (int j = 0; j < kEPT; ++j) {
    float t = ls[j] + ld[j];
    t = t > 0.f ? t : 0.2f * t;
    float w = __expf(t);
    if (ok[j]) {
      Wet[base + j * kNTH] = (_Float16)w;
      unsafeAtomicAdd(&DENf[(long long)(drb + d[j]) * 2], w);
    }
  }
}

// ---------------------------------------------------------------------------
// edgeB: streamed W16 read + DEN {den,batch} gather + x-rec gather;
// alpha*x into LDS [k][64 batches]; cnt sweep; dump to P4.
template <int TYPE>
__device__ __forceinline__ void ebflow(
    int bIdx,
    const int* __restrict__ sp, const int* __restrict__ dp,
    const uint4* __restrict__ srq4, const uint2* __restrict__ srq2,
    const _Float16* __restrict__ Wet, const float2* __restrict__ DEN2,
    int drb, int dlen, float* lp)
{
  constexpr int K = (TYPE == 0) ? 8 : ((TYPE == 1) ? 13 : 4);
  const int tid = threadIdx.x;
  const int lane = tid & 63;
  int base = bIdx * 256 + tid;

  int s[kEPT], d[kEPT]; bool ok[kEPT];
#pragma unroll
  for (int j = 0; j < kEPT; ++j) {
    int e = base + j * kNTH;
    ok[j] = e < kE;
    int ee = ok[j] ? e : 0;
    s[j] = sp[ee]; d[j] = dp[ee];
  }
  float w[kEPT];
#pragma unroll
  for (int j = 0; j < kEPT; ++j) {
    int e = base + j * kNTH;
    w[j] = (float)Wet[ok[j] ? e : 0];
  }
  uint4 q0[kEPT], q1[kEPT]; uint2 r2v[kEPT];
#pragma unroll
  for (int j = 0; j < kEPT; ++j) {
    if (TYPE == 0) {
      q0[j] = srq4[s[j]];
    } else if (TYPE == 1) {
      q0[j] = srq4[(long long)s[j] * 2];
      q1[j] = srq4[(long long)s[j] * 2 + 1];
    } else {
      r2v[j] = srq2[s[j]];
    }
  }
  float2 f2[kEPT];
#pragma unroll
  for (int j = 0; j < kEPT; ++j) f2[j] = DEN2[drb + d[j]];

#pragma unroll
  for (int j = 0; j < kEPT; ++j) {
    if (!ok[j]) continue;
    int b = (int)f2[j].y;
    float alpha = w[j] / fmaxf(f2[j].x, 1e-16f);
    float xv[K];
    if (TYPE == 0) {
      const _Float16* h = (const _Float16*)&q0[j];
#pragma unroll
      for (int k = 0; k < 8; ++k) xv[k] = (float)h[k];
    } else if (TYPE == 1) {
      const _Float16* h = (const _Float16*)&q0[j];
#pragma unroll
      for (int k = 0; k < 8; ++k) xv[k] = (float)h[k];
      const _Float16* h2 = (const _Float16*)&q1[j];
#pragma unroll
      for (int k = 0; k < 5; ++k) xv[8 + k] = (float)h2[k];
    } else {
      const _Float16* h = (const _Float16*)&r2v[j];
#pragma unroll
      for (int k = 0; k < 4; ++k) xv[k] = (float)h[k];
    }
#pragma unroll
    for (int k = 0; k < K; ++k) atomicAdd(lp + k * 64 + b, alpha * xv[k]);
  }

  // cnt: dense sweep of DEN {den,batch}; wave-segmented scan, one LDS
  // atomic per batch run (batch ids sorted by node index).
  for (int base2 = bIdx * 256 + (tid & ~63); base2 < dlen; base2 += kNTH) {
    int j2 = base2 + lane;
    bool a2 = j2 < dlen;
    float2 r2 = a2 ? DEN2[drb + j2] : make_float2(0.f, 0.f);
    int b2 = a2 ? (int)r2.y : (64 + lane);
    int v = (a2 && r2.x > 0.f) ? 1 : 0;
#pragma unroll
    for (int d2 = 1; d2 < 64; d2 <<= 1) {
      int ob = __shfl_up(b2, d2);
      int ov = __shfl_up(v, d2);
      if (lane >= d2 && ob == b2) v += ov;
    }
    int bn = __shfl_down(b2, 1);
    if (((lane == 63) || (bn != b2)) && v > 0) atomicAdd(lp + 1024 + b2, (float)v);
  }
}

__global__ __launch_bounds__(256, 4) void edgeB_kernel(
    const int* s0, const int* s1, const int* s2,
    const int* s3, const int* s4, const int* s5,
    const int* d0, const int* d1, const int* d2,
    const int* d3, const int* d4, const int* d5,
    const uint4* SRVq, const uint4* STq, const uint2* SRq,
    const _Float16* __restrict__ W16, const float2* __restrict__ DEN2,
    float* __restrict__ P4)
{
  __shared__ float lp[kSLOT];
  for (int j = threadIdx.x; j < kSLOT; j += 256) lp[j] = 0.f;
  __syncthreads();
  int et = blockIdx.x / kNBE;
  int bIdx = blockIdx.x - et * kNBE;
  const _Float16* Wet = W16 + (long long)et * kE;
  constexpr int KK[6] = {13, 8, 4, 13, 8, 4};
  switch (et) {
    case 0: ebflow<1>(bIdx, s0, d0, SRVq, nullptr, Wet, DEN2, 0,       100000, lp); break;
    case 1: ebflow<0>(bIdx, s1, d1, STq,  nullptr, Wet, DEN2, 100000,  200000, lp); break;
    case 2: ebflow<2>(bIdx, s2, d2, nullptr, SRq,  Wet, DEN2, 300000,  200000, lp); break;
    case 3: ebflow<1>(bIdx, s3, d3, SRVq, nullptr, Wet, DEN2, 500000,  300000, lp); break;
    case 4: ebflow<0>(bIdx, s4, d4, STq,  nullptr, Wet, DEN2, 800000,  300000, lp); break;
    default: ebflow<2>(bIdx, s5, d5, nullptr, SRq, Wet, DEN2, 1100000, 100000, lp); break;
  }
  __syncthreads();
  int K = KK[et];
  float* slab = P4 + (long long)(blockIdx.x & 3) * kPSZ + (long long)et * kSLOT;
  for (int i = threadIdx.x; i < kSLOT; i += 256) {
    if (i >= K * 64 && i < 1024) continue;
    float v = lp[i];
    if (v != 0.f) unsafeAtomicAdd(&slab[i], v);
  }
}

// ---------------------------------------------------------------------------
// tail: P4 sum + pooled GAT rows (reads Cws) + player MLP + output GEMV
__global__ __launch_bounds__(128) void tail_kernel(
    const int* __restrict__ bt, const int* __restrict__ brv, const int* __restrict__ br,
    const float* __restrict__ xp,
    const float* __restrict__ fc1W, const float* __restrict__ fc1b,
    const float* __restrict__ fc2W, const float* __restrict__ fc2b,
    const float* __restrict__ outW, const float* __restrict__ outb,
    const float* __restrict__ b_rv2t, const float* __restrict__ b_r2t,
    const float* __restrict__ b_t2rv, const float* __restrict__ b_r2rv,
    const float* __restrict__ b_rv2r, const float* __restrict__ b_t2r,
    const float* __restrict__ Cws, const float* __restrict__ P4,
    float* __restrict__ out)
{
  int b = blockIdx.x, tid = threadIdx.x;
  __shared__ float xrow[512];
  __shared__ float p1s[128];
  __shared__ float xps[64];
  __shared__ float psA[15], psB[15];
  __shared__ int cnts[3];

  if (tid < 64) xps[tid] = xp[b * 64 + tid];
  if (tid >= 64 && tid < 67) {
    int t = tid - 64;
    const int* ba = (t == 0) ? bt : (t == 1 ? brv : br);
    int N = (t == 0) ? kNT : (t == 1 ? kNRV : kNR);
    cnts[t] = lowb(ba, N, b + 1) - lowb(ba, N, b);
  }
  __syncthreads();

  // player branch
  float a = fc1b[tid];
  for (int k = 0; k < 64; ++k) a += xps[k] * fc1W[k * 128 + tid];
  p1s[tid] = fmaxf(a, 0.f);
  __syncthreads();
  float a2 = fc2b[tid];
  for (int k = 0; k < 128; ++k) a2 += p1s[k] * fc2W[k * 128 + tid];
  xrow[384 + tid] = fmaxf(a2, 0.f);

  const int etA[3] = {0, 1, 3}, etB[3] = {5, 2, 4};
  const int KAv[3] = {13, 8, 13}, KBv[3] = {4, 4, 8};
  for (int t3 = 0; t3 < 3; ++t3) {
    __syncthreads();
    int eA = etA[t3], eB = etB[t3];
    if (tid < 15) {
      int idx = (tid < 14) ? (tid * 64 + b) : (1024 + b);
      float sum = 0.f;
#pragma unroll
      for (int c = 0; c < 4; ++c) sum += P4[c * kPSZ + eA * kSLOT + idx];
      psA[tid] = sum;
    } else if (tid < 30) {
      int t = tid - 15;
      int idx = (t < 14) ? (t * 64 + b) : (1024 + b);
      float sum = 0.f;
#pragma unroll
      for (int c = 0; c < 4; ++c) sum += P4[c * kPSZ + eB * kSLOT + idx];
      psB[t] = sum;
    }
    __syncthreads();
    int KA = KAv[t3], KB = KBv[t3];
    const float* CA = Cws + eA * 2176;
    const float* CB = Cws + eB * 2176;
    float v = psA[14] * CA[2048 + tid] + psB[14] * CB[2048 + tid];
    for (int k = 0; k < KA; ++k) v += psA[k] * CA[k * 128 + tid];
    for (int k = 0; k < KB; ++k) v += psB[k] * CB[k * 128 + tid];
    float cnt = (float)max(cnts[t3], 1);
    const float* bb1 = (t3 == 0) ? b_rv2t : (t3 == 1 ? b_t2rv : b_rv2r);
    const float* bb2 = (t3 == 0) ? b_r2t  : (t3 == 1 ? b_r2rv : b_t2r);
    xrow[t3 * 128 + tid] = v / cnt + bb1[tid] + bb2[tid];
  }
  __syncthreads();

  // output GEMV: out[b, c] for c = tid + 128q
#pragma unroll
  for (int q = 0; q < 4; ++q) {
    int c = q * 128 + tid;
    float acc = outb[c];
#pragma unroll 8
    for (int k = 0; k < 512; ++k) acc += xrow[k] * outW[k * 512 + c];
    out[b * 512 + c] = acc;
  }
}

// ---------------------------------------------------------------------------
extern "C" void kernel_launch(void* const* d_in, const int* in_sizes, int n_in,
                              void* d_out, int out_size, void* d_ws, size_t ws_size,
                              hipStream_t stream) {
  const float* x_tile   = (const float*)d_in[0];
  const float* x_rv     = (const float*)d_in[1];
  const float* x_road   = (const float*)d_in[2];
  const float* x_player = (const float*)d_in[3];
  const float* enc_t_W  = (const float*)d_in[4];
  const float* enc_t_b  = (const float*)d_in[5];
  const float* enc_rv_W = (const float*)d_in[6];
  const float* enc_rv_b = (const float*)d_in[7];
  const float* enc_r_W  = (const float*)d_in[8];
  const float* enc_r_b  = (const float*)d_in[9];
  const float* W[6]; const float* As[6]; const float* Ad[6]; const float* Bb[6];
  for (int et = 0; et < 6; ++et) {
    W[et]  = (const float*)d_in[10 + 4 * et];
    As[et] = (const float*)d_in[11 + 4 * et];
    Ad[et] = (const float*)d_in[12 + 4 * et];
    Bb[et] = (const float*)d_in[13 + 4 * et];
  }
  const float* fc1W = (const float*)d_in[34];
  const float* fc1b = (const float*)d_in[35];
  const float* fc2W = (const float*)d_in[36];
  const float* fc2b = (const float*)d_in[37];
  const float* outW = (const float*)d_in[38];
  const float* outb = (const float*)d_in[39];
  const int* esrc[6]; const int* edst[6];
  for (int et = 0; et < 6; ++et) {
    esrc[et] = (const int*)d_in[40 + 2 * et];
    edst[et] = (const int*)d_in[41 + 2 * et];
  }
  const int* batch_t  = (const int*)d_in[52];
  const int* batch_rv = (const int*)d_in[53];
  const int* batch_r  = (const int*)d_in[54];

  float* wsF = (float*)d_ws;
  float* Cws  = wsF + OFF_C;
  float* vsw  = wsF + OFF_VS;
  float* vdw  = wsF + OFF_VD;
  float* P4   = wsF + OFF_P4;
  float* LS6  = wsF + OFF_LS6;
  float* LD6  = wsF + OFF_LD6;
  _Float16* W16 = (_Float16*)(wsF + OFF_W16);
  float* DENf = wsF + OFF_DEN;
  float2* DEN2 = (float2*)(wsF + OFF_DEN);
  uint4* SRVq = (uint4*)(wsF + OFF_SRV);
  uint4* STq  = (uint4*)(wsF + OFF_ST);
  uint2* SRq  = (uint2*)(wsF + OFF_SR);
  float* out  = (float*)d_out;

  precompute_kernel<<<6, 256, 0, stream>>>(
      enc_t_W, enc_t_b, enc_rv_W, enc_rv_b, enc_r_W, enc_r_b,
      W[0], As[0], Ad[0], W[1], As[1], Ad[1], W[2], As[2], Ad[2],
      W[3], As[3], Ad[3], W[4], As[4], Ad[4], W[5], As[5], Ad[5],
      Cws, vsw, vdw, P4);

  prep_kernel<<<(kNT + kNRV + kNR + 255) / 256, 256, 0, stream>>>(
      x_tile, x_rv, x_road, batch_t, batch_rv, batch_r, vsw, vdw,
      SRVq, STq, SRq, LS6, LD6, DEN2);

  edgeA_kernel<<<6 * kNBE, 256, 0, stream>>>(
      esrc[0], esrc[1], esrc[2], esrc[3], esrc[4], esrc[5],
      edst[0], edst[1], edst[2], edst[3], edst[4], edst[5],
      LS6, LD6, W16, DENf);

  edgeB_kernel<<<6 * kNBE, 256, 0, stream>>>(
      esrc[0], esrc[1], esrc[2], esrc[3], esrc[4], esrc[5],
      edst[0], edst[1], edst[2], edst[3], edst[4], edst[5],
      SRVq, STq, SRq, W16, DEN2, P4);

  tail_kernel<<<64, 128, 0, stream>>>(
      batch_t, batch_rv, batch_r, x_player,
      fc1W, fc1b, fc2W, fc2b, outW, outb,
      Bb[0], Bb[5], Bb[1], Bb[2], Bb[3], Bb[4],
      Cws, P4, out);

  (void)in_sizes; (void)n_in; (void)out_size; (void)ws_size;
}

// Round 7
// 504.089 us; speedup vs baseline: 1.2657x; 1.1489x over previous
//
#include <hip/hip_runtime.h>

// ---------------------------------------------------------------------------
// GNNQNetwork hetero-GAT, MI355X fp32. Round 11.
//
// R11 = R10 with the tail GEMV re-parallelized (R10 counters: tail was a
// hidden 140us kernel since R9 — 64 blocks x 128 thr = 1.45% occupancy,
// 2048 strided L2 loads/thread, latency-bound). Grid 64 -> 512 blocks:
// block (b, half) redundantly computes xrow for graph b (cheap ~250 MACs)
// then computes 64 output columns via half-K slices + LDS combine
// (256 MACs/thread, 8x parallelism). Everything else identical to R10.
// ---------------------------------------------------------------------------

constexpr int kNT = 100000, kNRV = 200000, kNR = 300000, kE = 400000;
constexpr int kSLOT = 1088;        // per-et P tile: 16x64 acc + 64 cnt
constexpr int kPSZ  = 6 * kSLOT;   // 6528
constexpr int kNBE  = 342;         // blocks per edge type
constexpr int kNTH  = kNBE * 256;  // 87552 threads per edge type
constexpr int kEPT  = 5;           // edge slots per thread (5*87552 >= 400k)

// workspace offsets in 4-byte units (total 34.56 MB <= 34.61 proven)
constexpr long long OFF_C    = 0;        // 6*2176 C rows + bias@2048
constexpr long long OFF_VS   = 13056;    // 6*20
constexpr long long OFF_VD   = 13176;    // 6*20
constexpr long long OFF_P4   = 13296;    // 4 staged P copies: 4*6528 = 26112
constexpr long long OFF_LS6  = 39408;    // dense src logits, 1.2M
constexpr long long OFF_LD6  = 1239408;  // dense dst logits, 1.2M
constexpr long long OFF_W16  = 2439408;  // 2.4M halves = 1.2M floats
constexpr long long OFF_DEN  = 3639408;  // {den,batch} float2 x 1.2M = 2.4M
constexpr long long OFF_SRV  = 6039408;  // rv recs: 200k*8 floats (32B)
constexpr long long OFF_ST   = 7639408;  // t recs: 100k*4 floats (16B)
constexpr long long OFF_SR   = 8039408;  // r recs: 300k*2 floats (8B)
// end 8639408 floats = 34.558 MB

// per-et tables. src type: rv,t,r,rv,t,r ; dst type: t,rv,rv,r,r,t
__constant__ const int kDRB[6]  = {0, 100000, 300000, 500000, 800000, 1100000};
__constant__ const int kDLEN[6] = {100000, 200000, 200000, 300000, 300000, 100000};
__constant__ const int kLSB6[6] = {0, 400000, 600000, 200000, 500000, 900000};

// ---------------------------------------------------------------------------
__device__ __forceinline__ int lowb(const int* a, int n, int v) {
  int lo = 0, hi = n;
  while (lo < hi) { int mid = (lo + hi) >> 1; if (a[mid] < v) lo = mid + 1; else hi = mid; }
  return lo;
}

static __device__ __forceinline__ unsigned p2h(float a, float b) {
  _Float16 ha = (_Float16)a, hb = (_Float16)b;
  unsigned short ua = __builtin_bit_cast(unsigned short, ha);
  unsigned short ub = __builtin_bit_cast(unsigned short, hb);
  return (unsigned)ua | ((unsigned)ub << 16);
}

// ---------------------------------------------------------------------------
// precompute: C = enc @ W (rows 0..K-1, bias row @2048), vsw/vdw, P4 zero
__global__ __launch_bounds__(256) void precompute_kernel(
    const float* encW_t, const float* encb_t,
    const float* encW_rv, const float* encb_rv,
    const float* encW_r, const float* encb_r,
    const float* W0, const float* as0, const float* ad0,
    const float* W1, const float* as1, const float* ad1,
    const float* W2, const float* as2, const float* ad2,
    const float* W3, const float* as3, const float* ad3,
    const float* W4, const float* as4, const float* ad4,
    const float* W5, const float* as5, const float* ad5,
    float* Cws, float* vsw, float* vdw, float* P4)
{
  const float* encW[3] = {encW_t, encW_rv, encW_r};
  const float* encb[3] = {encb_t, encb_rv, encb_r};
  const int    Ks[3]   = {8, 13, 4};
  const float* Wv[6]  = {W0, W1, W2, W3, W4, W5};
  const float* asv[6] = {as0, as1, as2, as3, as4, as5};
  const float* adv[6] = {ad0, ad1, ad2, ad3, ad4, ad5};
  const int srcT[6] = {1, 0, 2, 1, 0, 2};
  const int dstT[6] = {0, 1, 1, 2, 2, 0};

  __shared__ float Cl[2176];
  __shared__ float wv[128];

  int et = blockIdx.x;
  int tid = threadIdx.x;
  int st = srcT[et], dt = dstT[et];
  const float* eW = encW[st];
  const float* eB = encb[st];
  int K = Ks[st];
  const float* W = Wv[et];
  const float* a_s = asv[et];
  const float* a_d = adv[et];
  float* Cslot = Cws + et * 2176;

  // zero P4 (grid-strided across the 6 blocks)
  for (int i = et * 256 + tid; i < 4 * kPSZ; i += 6 * 256) P4[i] = 0.f;

  for (int idx = tid; idx < (K + 1) * 128; idx += 256) {
    int r = idx >> 7, j = idx & 127;
    const float* row = (r < K) ? (eW + r * 128) : eB;
    float acc = 0.f;
    for (int m = 0; m < 128; ++m) acc += row[m] * W[m * 128 + j];
    int o = (r < K) ? (r * 128 + j) : (2048 + j);
    Cl[o] = acc;
    Cslot[o] = acc;
  }
  if (tid < 128) {
    float acc = 0.f;
    for (int j = 0; j < 128; ++j) acc += W[tid * 128 + j] * a_d[j];
    wv[tid] = acc;
  }
  __syncthreads();
  if (tid <= K) {
    const float* row = (tid < K) ? (Cl + tid * 128) : (Cl + 2048);
    float acc = 0.f;
    for (int j = 0; j < 128; ++j) acc += row[j] * a_s[j];
    vsw[et * 20 + (tid < K ? tid : 16)] = acc;
  }
  int KD = Ks[dt];
  if (tid >= 32 && tid <= 32 + KD) {
    int k = tid - 32;
    const float* row = (k < KD) ? (encW[dt] + k * 128) : encb[dt];
    float acc = 0.f;
    for (int m = 0; m < 128; ++m) acc += row[m] * wv[m];
    vdw[et * 20 + (k < KD ? k : 16)] = acc;
  }
}

// ---------------------------------------------------------------------------
// prep: per node, write x-only src recs, dense LS6/LD6 logits, DEN {0, b}.
__global__ __launch_bounds__(256) void prep_kernel(
    const float* __restrict__ x_t, const float* __restrict__ x_rv,
    const float* __restrict__ x_r,
    const int* __restrict__ bt, const int* __restrict__ brv,
    const int* __restrict__ br,
    const float* __restrict__ vsw, const float* __restrict__ vdw,
    uint4* __restrict__ SRVq, uint4* __restrict__ STq, uint2* __restrict__ SRq,
    float* __restrict__ LS6, float* __restrict__ LD6,
    float2* __restrict__ DEN)
{
  int n = blockIdx.x * 256 + threadIdx.x;
  if (n >= kNT + kNRV + kNR) return;
  if (n < kNT) {
    // tile: src roles et1,et4 (K=8); dst roles et0,et5
    const float* xr = x_t + n * 8;
    float bf = (float)bt[n];
    const float* vsA = vsw + 1 * 20, *vsB = vsw + 4 * 20;
    const float* vdA = vdw + 0 * 20, *vdB = vdw + 5 * 20;
    float x[8]; float a0 = 0, a1 = 0, a2 = 0, a3 = 0;
#pragma unroll
    for (int k = 0; k < 8; ++k) {
      x[k] = xr[k];
      a0 += x[k] * vsA[k]; a1 += x[k] * vsB[k];
      a2 += x[k] * vdA[k]; a3 += x[k] * vdB[k];
    }
    STq[n] = make_uint4(p2h(x[0], x[1]), p2h(x[2], x[3]),
                        p2h(x[4], x[5]), p2h(x[6], x[7]));
    LS6[400000 + n] = a0 + vsA[16];
    LS6[500000 + n] = a1 + vsB[16];
    LD6[n] = a2 + vdA[16];
    LD6[1100000 + n] = a3 + vdB[16];
    DEN[n] = make_float2(0.f, bf);
    DEN[1100000 + n] = make_float2(0.f, bf);
  } else if (n < kNT + kNRV) {
    int m = n - kNT;
    // rv: src roles et0,et3 (K=13); dst roles et1,et2
    const float* xr = x_rv + m * 13;
    float bf = (float)brv[m];
    const float* vsA = vsw + 0 * 20, *vsB = vsw + 3 * 20;
    const float* vdA = vdw + 1 * 20, *vdB = vdw + 2 * 20;
    float x[13]; float a0 = 0, a1 = 0, a2 = 0, a3 = 0;
#pragma unroll
    for (int k = 0; k < 13; ++k) {
      x[k] = xr[k];
      a0 += x[k] * vsA[k]; a1 += x[k] * vsB[k];
      a2 += x[k] * vdA[k]; a3 += x[k] * vdB[k];
    }
    SRVq[(long long)m * 2] =
        make_uint4(p2h(x[0], x[1]), p2h(x[2], x[3]), p2h(x[4], x[5]), p2h(x[6], x[7]));
    SRVq[(long long)m * 2 + 1] =
        make_uint4(p2h(x[8], x[9]), p2h(x[10], x[11]), p2h(x[12], 0.f), 0);
    LS6[m] = a0 + vsA[16];
    LS6[200000 + m] = a1 + vsB[16];
    LD6[100000 + m] = a2 + vdA[16];
    LD6[300000 + m] = a3 + vdB[16];
    DEN[100000 + m] = make_float2(0.f, bf);
    DEN[300000 + m] = make_float2(0.f, bf);
  } else {
    int m = n - kNT - kNRV;
    // road: src roles et2,et5 (K=4); dst roles et3,et4
    const float* xr = x_r + m * 4;
    float bf = (float)br[m];
    const float* vsA = vsw + 2 * 20, *vsB = vsw + 5 * 20;
    const float* vdA = vdw + 3 * 20, *vdB = vdw + 4 * 20;
    float x[4]; float a0 = 0, a1 = 0, a2 = 0, a3 = 0;
#pragma unroll
    for (int k = 0; k < 4; ++k) {
      x[k] = xr[k];
      a0 += x[k] * vsA[k]; a1 += x[k] * vsB[k];
      a2 += x[k] * vdA[k]; a3 += x[k] * vdB[k];
    }
    SRq[m] = make_uint2(p2h(x[0], x[1]), p2h(x[2], x[3]));
    LS6[600000 + m] = a0 + vsA[16];
    LS6[900000 + m] = a1 + vsB[16];
    LD6[500000 + m] = a2 + vdA[16];
    LD6[800000 + m] = a3 + vdB[16];
    DEN[500000 + m] = make_float2(0.f, bf);
    DEN[800000 + m] = make_float2(0.f, bf);
  }
}

// ---------------------------------------------------------------------------
__device__ __forceinline__ void pickSD(
    int et,
    const int* s0, const int* s1, const int* s2,
    const int* s3, const int* s4, const int* s5,
    const int* d0, const int* d1, const int* d2,
    const int* d3, const int* d4, const int* d5,
    const int*& sp, const int*& dp)
{
  switch (et) {
    case 0: sp = s0; dp = d0; break;
    case 1: sp = s1; dp = d1; break;
    case 2: sp = s2; dp = d2; break;
    case 3: sp = s3; dp = d3; break;
    case 4: sp = s4; dp = d4; break;
    default: sp = s5; dp = d5; break;
  }
}

// ---------------------------------------------------------------------------
// edgeA: w = exp(leaky(ls+ld)); W16[i] = w (streamed); DEN.x += w (atomic).
// Read-only gathers (LS6, LD6) fully separated from the atomic region (DEN).
__global__ __launch_bounds__(256, 8) void edgeA_kernel(
    const int* s0, const int* s1, const int* s2,
    const int* s3, const int* s4, const int* s5,
    const int* d0, const int* d1, const int* d2,
    const int* d3, const int* d4, const int* d5,
    const float* __restrict__ LS6, const float* __restrict__ LD6,
    _Float16* __restrict__ W16, float* __restrict__ DENf)
{
  int et = blockIdx.x / kNBE;
  int bIdx = blockIdx.x - et * kNBE;
  const int* sp; const int* dp;
  pickSD(et, s0, s1, s2, s3, s4, s5, d0, d1, d2, d3, d4, d5, sp, dp);
  const float* Lsrc = LS6 + kLSB6[et];
  const float* Ldst = LD6 + kDRB[et];
  const int drb = kDRB[et];
  _Float16* Wet = W16 + (long long)et * kE;
  int base = bIdx * 256 + (int)threadIdx.x;

  int s[kEPT], d[kEPT]; bool ok[kEPT];
#pragma unroll
  for (int j = 0; j < kEPT; ++j) {
    int e = base + j * kNTH;
    ok[j] = e < kE;
    int ee = ok[j] ? e : 0;
    s[j] = sp[ee]; d[j] = dp[ee];
  }
  float ls[kEPT];
#pragma unroll
  for (int j = 0; j < kEPT; ++j) ls[j] = Lsrc[s[j]];
  float ld[kEPT];
#pragma unroll
  for (int j = 0; j < kEPT; ++j) ld[j] = Ldst[d[j]];
#pragma unroll
  for (int j = 0; j < kEPT; ++j) {
    float t = ls[j] + ld[j];
    t = t > 0.f ? t : 0.2f * t;
    float w = __expf(t);
    if (ok[j]) {
      Wet[base + j * kNTH] = (_Float16)w;
      unsafeAtomicAdd(&DENf[(long long)(drb + d[j]) * 2], w);
    }
  }
}

// ---------------------------------------------------------------------------
// edgeB: streamed W16 read + DEN {den,batch} gather + x-rec gather;
// alpha*x into LDS [k][64 batches]; cnt sweep; dump to P4.
template <int TYPE>
__device__ __forceinline__ void ebflow(
    int bIdx,
    const int* __restrict__ sp, const int* __restrict__ dp,
    const uint4* __restrict__ srq4, const uint2* __restrict__ srq2,
    const _Float16* __restrict__ Wet, const float2* __restrict__ DEN2,
    int drb, int dlen, float* lp)
{
  constexpr int K = (TYPE == 0) ? 8 : ((TYPE == 1) ? 13 : 4);
  const int tid = threadIdx.x;
  const int lane = tid & 63;
  int base = bIdx * 256 + tid;

  int s[kEPT], d[kEPT]; bool ok[kEPT];
#pragma unroll
  for (int j = 0; j < kEPT; ++j) {
    int e = base + j * kNTH;
    ok[j] = e < kE;
    int ee = ok[j] ? e : 0;
    s[j] = sp[ee]; d[j] = dp[ee];
  }
  float w[kEPT];
#pragma unroll
  for (int j = 0; j < kEPT; ++j) {
    int e = base + j * kNTH;
    w[j] = (float)Wet[ok[j] ? e : 0];
  }
  uint4 q0[kEPT], q1[kEPT]; uint2 r2v[kEPT];
#pragma unroll
  for (int j = 0; j < kEPT; ++j) {
    if (TYPE == 0) {
      q0[j] = srq4[s[j]];
    } else if (TYPE == 1) {
      q0[j] = srq4[(long long)s[j] * 2];
      q1[j] = srq4[(long long)s[j] * 2 + 1];
    } else {
      r2v[j] = srq2[s[j]];
    }
  }
  float2 f2[kEPT];
#pragma unroll
  for (int j = 0; j < kEPT; ++j) f2[j] = DEN2[drb + d[j]];

#pragma unroll
  for (int j = 0; j < kEPT; ++j) {
    if (!ok[j]) continue;
    int b = (int)f2[j].y;
    float alpha = w[j] / fmaxf(f2[j].x, 1e-16f);
    float xv[K];
    if (TYPE == 0) {
      const _Float16* h = (const _Float16*)&q0[j];
#pragma unroll
      for (int k = 0; k < 8; ++k) xv[k] = (float)h[k];
    } else if (TYPE == 1) {
      const _Float16* h = (const _Float16*)&q0[j];
#pragma unroll
      for (int k = 0; k < 8; ++k) xv[k] = (float)h[k];
      const _Float16* h2 = (const _Float16*)&q1[j];
#pragma unroll
      for (int k = 0; k < 5; ++k) xv[8 + k] = (float)h2[k];
    } else {
      const _Float16* h = (const _Float16*)&r2v[j];
#pragma unroll
      for (int k = 0; k < 4; ++k) xv[k] = (float)h[k];
    }
#pragma unroll
    for (int k = 0; k < K; ++k) atomicAdd(lp + k * 64 + b, alpha * xv[k]);
  }

  // cnt: dense sweep of DEN {den,batch}; wave-segmented scan, one LDS
  // atomic per batch run (batch ids sorted by node index).
  for (int base2 = bIdx * 256 + (tid & ~63); base2 < dlen; base2 += kNTH) {
    int j2 = base2 + lane;
    bool a2 = j2 < dlen;
    float2 r2 = a2 ? DEN2[drb + j2] : make_float2(0.f, 0.f);
    int b2 = a2 ? (int)r2.y : (64 + lane);
    int v = (a2 && r2.x > 0.f) ? 1 : 0;
#pragma unroll
    for (int d2 = 1; d2 < 64; d2 <<= 1) {
      int ob = __shfl_up(b2, d2);
      int ov = __shfl_up(v, d2);
      if (lane >= d2 && ob == b2) v += ov;
    }
    int bn = __shfl_down(b2, 1);
    if (((lane == 63) || (bn != b2)) && v > 0) atomicAdd(lp + 1024 + b2, (float)v);
  }
}

__global__ __launch_bounds__(256, 4) void edgeB_kernel(
    const int* s0, const int* s1, const int* s2,
    const int* s3, const int* s4, const int* s5,
    const int* d0, const int* d1, const int* d2,
    const int* d3, const int* d4, const int* d5,
    const uint4* SRVq, const uint4* STq, const uint2* SRq,
    const _Float16* __restrict__ W16, const float2* __restrict__ DEN2,
    float* __restrict__ P4)
{
  __shared__ float lp[kSLOT];
  for (int j = threadIdx.x; j < kSLOT; j += 256) lp[j] = 0.f;
  __syncthreads();
  int et = blockIdx.x / kNBE;
  int bIdx = blockIdx.x - et * kNBE;
  const _Float16* Wet = W16 + (long long)et * kE;
  constexpr int KK[6] = {13, 8, 4, 13, 8, 4};
  switch (et) {
    case 0: ebflow<1>(bIdx, s0, d0, SRVq, nullptr, Wet, DEN2, 0,       100000, lp); break;
    case 1: ebflow<0>(bIdx, s1, d1, STq,  nullptr, Wet, DEN2, 100000,  200000, lp); break;
    case 2: ebflow<2>(bIdx, s2, d2, nullptr, SRq,  Wet, DEN2, 300000,  200000, lp); break;
    case 3: ebflow<1>(bIdx, s3, d3, SRVq, nullptr, Wet, DEN2, 500000,  300000, lp); break;
    case 4: ebflow<0>(bIdx, s4, d4, STq,  nullptr, Wet, DEN2, 800000,  300000, lp); break;
    default: ebflow<2>(bIdx, s5, d5, nullptr, SRq, Wet, DEN2, 1100000, 100000, lp); break;
  }
  __syncthreads();
  int K = KK[et];
  float* slab = P4 + (long long)(blockIdx.x & 3) * kPSZ + (long long)et * kSLOT;
  for (int i = threadIdx.x; i < kSLOT; i += 256) {
    if (i >= K * 64 && i < 1024) continue;
    float v = lp[i];
    if (v != 0.f) unsafeAtomicAdd(&slab[i], v);
  }
}

// ---------------------------------------------------------------------------
// tail: grid 64 graphs x 8 column-groups. Each block redundantly builds
// xrow for its graph (player MLP + P4 sums + pooled GAT rows, ~250 MACs),
// then computes 64 output columns as two half-K dot slices + LDS combine.
__global__ __launch_bounds__(128) void tail_kernel(
    const int* __restrict__ bt, const int* __restrict__ brv, const int* __restrict__ br,
    const float* __restrict__ xp,
    const float* __restrict__ fc1W, const float* __restrict__ fc1b,
    const float* __restrict__ fc2W, const float* __restrict__ fc2b,
    const float* __restrict__ outW, const float* __restrict__ outb,
    const float* __restrict__ b_rv2t, const float* __restrict__ b_r2t,
    const float* __restrict__ b_t2rv, const float* __restrict__ b_r2rv,
    const float* __restrict__ b_rv2r, const float* __restrict__ b_t2r,
    const float* __restrict__ Cws, const float* __restrict__ P4,
    float* __restrict__ out)
{
  int b = blockIdx.x >> 3;
  int half = blockIdx.x & 7;
  int tid = threadIdx.x;
  __shared__ float xrow[512];
  __shared__ float p1s[128];
  __shared__ float xps[64];
  __shared__ float psA[15], psB[15];
  __shared__ float part[128];
  __shared__ int cnts[3];

  if (tid < 64) xps[tid] = xp[b * 64 + tid];
  if (tid >= 64 && tid < 67) {
    int t = tid - 64;
    const int* ba = (t == 0) ? bt : (t == 1 ? brv : br);
    int N = (t == 0) ? kNT : (t == 1 ? kNRV : kNR);
    cnts[t] = lowb(ba, N, b + 1) - lowb(ba, N, b);
  }
  __syncthreads();

  // player branch
  float a = fc1b[tid];
  for (int k = 0; k < 64; ++k) a += xps[k] * fc1W[k * 128 + tid];
  p1s[tid] = fmaxf(a, 0.f);
  __syncthreads();
  float a2 = fc2b[tid];
  for (int k = 0; k < 128; ++k) a2 += p1s[k] * fc2W[k * 128 + tid];
  xrow[384 + tid] = fmaxf(a2, 0.f);

  const int etA[3] = {0, 1, 3}, etB[3] = {5, 2, 4};
  const int KAv[3] = {13, 8, 13}, KBv[3] = {4, 4, 8};
  for (int t3 = 0; t3 < 3; ++t3) {
    __syncthreads();
    int eA = etA[t3], eB = etB[t3];
    if (tid < 15) {
      int idx = (tid < 14) ? (tid * 64 + b) : (1024 + b);
      float sum = 0.f;
#pragma unroll
      for (int c = 0; c < 4; ++c) sum += P4[c * kPSZ + eA * kSLOT + idx];
      psA[tid] = sum;
    } else if (tid < 30) {
      int t = tid - 15;
      int idx = (t < 14) ? (t * 64 + b) : (1024 + b);
      float sum = 0.f;
#pragma unroll
      for (int c = 0; c < 4; ++c) sum += P4[c * kPSZ + eB * kSLOT + idx];
      psB[t] = sum;
    }
    __syncthreads();
    int KA = KAv[t3], KB = KBv[t3];
    const float* CA = Cws + eA * 2176;
    const float* CB = Cws + eB * 2176;
    float v = psA[14] * CA[2048 + tid] + psB[14] * CB[2048 + tid];
    for (int k = 0; k < KA; ++k) v += psA[k] * CA[k * 128 + tid];
    for (int k = 0; k < KB; ++k) v += psB[k] * CB[k * 128 + tid];
    float cnt = (float)max(cnts[t3], 1);
    const float* bb1 = (t3 == 0) ? b_rv2t : (t3 == 1 ? b_t2rv : b_rv2r);
    const float* bb2 = (t3 == 0) ? b_r2t  : (t3 == 1 ? b_r2rv : b_t2r);
    xrow[t3 * 128 + tid] = v / cnt + bb1[tid] + bb2[tid];
  }
  __syncthreads();

  // output GEMV slice: 64 columns c = half*64 + (tid&63); k-half per tid>>6
  {
    int c = half * 64 + (tid & 63);
    int kh = tid >> 6;                       // 0 or 1
    const float* Wc = outW + c;
    float acc = 0.f;
    int k0 = kh * 256;
#pragma unroll 8
    for (int k = k0; k < k0 + 256; ++k) acc += xrow[k] * Wc[(long long)k * 512];
    part[tid] = acc;
    __syncthreads();
    if (tid < 64) out[b * 512 + c] = outb[c] + part[tid] + part[tid + 64];
  }
}

// ---------------------------------------------------------------------------
extern "C" void kernel_launch(void* const* d_in, const int* in_sizes, int n_in,
                              void* d_out, int out_size, void* d_ws, size_t ws_size,
                              hipStream_t stream) {
  const float* x_tile   = (const float*)d_in[0];
  const float* x_rv     = (const float*)d_in[1];
  const float* x_road   = (const float*)d_in[2];
  const float* x_player = (const float*)d_in[3];
  const float* enc_t_W  = (const float*)d_in[4];
  const float* enc_t_b  = (const float*)d_in[5];
  const float* enc_rv_W = (const float*)d_in[6];
  const float* enc_rv_b = (const float*)d_in[7];
  const float* enc_r_W  = (const float*)d_in[8];
  const float* enc_r_b  = (const float*)d_in[9];
  const float* W[6]; const float* As[6]; const float* Ad[6]; const float* Bb[6];
  for (int et = 0; et < 6; ++et) {
    W[et]  = (const float*)d_in[10 + 4 * et];
    As[et] = (const float*)d_in[11 + 4 * et];
    Ad[et] = (const float*)d_in[12 + 4 * et];
    Bb[et] = (const float*)d_in[13 + 4 * et];
  }
  const float* fc1W = (const float*)d_in[34];
  const float* fc1b = (const float*)d_in[35];
  const float* fc2W = (const float*)d_in[36];
  const float* fc2b = (const float*)d_in[37];
  const float* outW = (const float*)d_in[38];
  const float* outb = (const float*)d_in[39];
  const int* esrc[6]; const int* edst[6];
  for (int et = 0; et < 6; ++et) {
    esrc[et] = (const int*)d_in[40 + 2 * et];
    edst[et] = (const int*)d_in[41 + 2 * et];
  }
  const int* batch_t  = (const int*)d_in[52];
  const int* batch_rv = (const int*)d_in[53];
  const int* batch_r  = (const int*)d_in[54];

  float* wsF = (float*)d_ws;
  float* Cws  = wsF + OFF_C;
  float* vsw  = wsF + OFF_VS;
  float* vdw  = wsF + OFF_VD;
  float* P4   = wsF + OFF_P4;
  float* LS6  = wsF + OFF_LS6;
  float* LD6  = wsF + OFF_LD6;
  _Float16* W16 = (_Float16*)(wsF + OFF_W16);
  float* DENf = wsF + OFF_DEN;
  float2* DEN2 = (float2*)(wsF + OFF_DEN);
  uint4* SRVq = (uint4*)(wsF + OFF_SRV);
  uint4* STq  = (uint4*)(wsF + OFF_ST);
  uint2* SRq  = (uint2*)(wsF + OFF_SR);
  float* out  = (float*)d_out;

  precompute_kernel<<<6, 256, 0, stream>>>(
      enc_t_W, enc_t_b, enc_rv_W, enc_rv_b, enc_r_W, enc_r_b,
      W[0], As[0], Ad[0], W[1], As[1], Ad[1], W[2], As[2], Ad[2],
      W[3], As[3], Ad[3], W[4], As[4], Ad[4], W[5], As[5], Ad[5],
      Cws, vsw, vdw, P4);

  prep_kernel<<<(kNT + kNRV + kNR + 255) / 256, 256, 0, stream>>>(
      x_tile, x_rv, x_road, batch_t, batch_rv, batch_r, vsw, vdw,
      SRVq, STq, SRq, LS6, LD6, DEN2);

  edgeA_kernel<<<6 * kNBE, 256, 0, stream>>>(
      esrc[0], esrc[1], esrc[2], esrc[3], esrc[4], esrc[5],
      edst[0], edst[1], edst[2], edst[3], edst[4], edst[5],
      LS6, LD6, W16, DENf);

  edgeB_kernel<<<6 * kNBE, 256, 0, stream>>>(
      esrc[0], esrc[1], esrc[2], esrc[3], esrc[4], esrc[5],
      edst[0], edst[1], edst[2], edst[3], edst[4], edst[5],
      SRVq, STq, SRq, W16, DEN2, P4);

  tail_kernel<<<64 * 8, 128, 0, stream>>>(
      batch_t, batch_rv, batch_r, x_player,
      fc1W, fc1b, fc2W, fc2b, outW, outb,
      Bb[0], Bb[5], Bb[1], Bb[2], Bb[3], Bb[4],
      Cws, P4, out);

  (void)in_sizes; (void)n_in; (void)out_size; (void)ws_size;
}